// Round 7
// baseline (407.150 us; speedup 1.0000x reference)
//
#include <hip/hip_runtime.h>

#define LL 2048
#define HH 2048
#define EE 4096
#define NS 16
#define RR 128
#define CT 32            // chunk timesteps
#define NC (LL / CT)     // 64 chunks

typedef __bf16 bf16x8 __attribute__((ext_vector_type(8)));
typedef float f32x4 __attribute__((ext_vector_type(4)));

__device__ __forceinline__ unsigned short f2bf(float f) {
  union { float f; unsigned int u; } v; v.f = f;
  unsigned int r = v.u + 0x7fffu + ((v.u >> 16) & 1u);
  return (unsigned short)(r >> 16);
}

__device__ __forceinline__ float bf2f(unsigned short u) {
  union { unsigned int i; float f; } v;
  v.i = ((unsigned int)u) << 16;
  return v.f;
}

// softplus via native transcendentals only (NO libm log1pf — non-inline ocml
// call forces VGPR save/restore in high-pressure epilogues)
__device__ __forceinline__ float softplus_fast(float x) {
  if (x > 20.0f) return x;
  float e = __builtin_amdgcn_exp2f(1.44269504f * x);
  return 0.69314718f * __builtin_amdgcn_logf(1.0f + e);
}

__device__ __forceinline__ void async_cp16(const unsigned short* g,
                                           unsigned short* l) {
  __builtin_amdgcn_global_load_lds(
      (const __attribute__((address_space(1))) unsigned int*)g,
      (__attribute__((address_space(3))) unsigned int*)l, 16, 0, 0);
}

// ============ fused prep: 5 bf16 casts, ONE launch ==========
// (ssm no longer zeroed: x_proj writes partial slabs, xreduce sums them.
//  out not zeroed: out_proj stores directly.)
#define P_C0 (LL * HH / 4)               // hs -> hsb
#define P_C1 (P_C0 + 2 * EE * HH / 4)    // w1 -> w1b
#define P_C2 (P_C1 + 160 * EE / 4)       // xw -> xwb
#define P_C3 (P_C2 + EE * RR / 4)        // dtw -> dtwb
#define P_C4 (P_C3 + HH * EE / 4)        // ow -> owb

__global__ __launch_bounds__(256) void prep_k(
    const float* __restrict__ hs, unsigned short* __restrict__ hsb,
    const float* __restrict__ w1, unsigned short* __restrict__ w1b,
    const float* __restrict__ xw, unsigned short* __restrict__ xwb,
    const float* __restrict__ dtw, unsigned short* __restrict__ dtwb,
    const float* __restrict__ ow, unsigned short* __restrict__ owb) {
  int i = blockIdx.x * 256 + threadIdx.x;
  const float* src;
  unsigned short* dst;
  int k;
  if (i < P_C0)      { src = hs;  dst = hsb;  k = i; }
  else if (i < P_C1) { src = w1;  dst = w1b;  k = i - P_C0; }
  else if (i < P_C2) { src = xw;  dst = xwb;  k = i - P_C1; }
  else if (i < P_C3) { src = dtw; dst = dtwb; k = i - P_C2; }
  else               { src = ow;  dst = owb;  k = i - P_C3; }
  float4 v = reinterpret_cast<const float4*>(src)[k];
  ushort4 o;
  o.x = f2bf(v.x); o.y = f2bf(v.y); o.z = f2bf(v.z); o.w = f2bf(v.w);
  reinterpret_cast<ushort4*>(dst)[k] = o;
}

// ============= 256x256 8-phase BT-GEMM (proven: in_proj 76-78us) ===========
// 512 threads = 8 waves (2Mx4N), per-wave 128x64. BK=64, dbuf LDS 128 KiB.
// 8 phases / 2 K-tiles; counted vmcnt(4)/vmcnt(6); kk-outer MFMA (dep dist 8).
// NOTE: atomic split-K epilogue measured ~95us for out_proj (cross-XCD atomic
// RMW serialization) — never split-K this kernel with atomics.
// EPI: 2 = in_proj (cols<EE -> f32 auxF; cols>=EE -> silu bf16 auxB)
template <int EPI>
__global__ __launch_bounds__(512, 2) void gemm256(
    const unsigned short* __restrict__ A,
    const unsigned short* __restrict__ B,
    float* __restrict__ C,
    int M, int N, int K, int tilesM, int splitk,
    float* __restrict__ auxF, unsigned short* __restrict__ auxB) {
  __shared__ __align__(16) unsigned short As[2][16384];
  __shared__ __align__(16) unsigned short Bs[2][16384];

  int bid = blockIdx.x;
  int tnInner = bid & 7;             // XCD-locality
  int rest = bid >> 3;
  int tm = rest % tilesM;
  int tn = (rest / tilesM) * 8 + tnInner;

  int Kslice = K / splitk;
  int k_begin = blockIdx.y * Kslice;
  int NT = Kslice / 64;              // even, >= 2

  int tid = threadIdx.x;
  int lane = tid & 63;
  int wave = tid >> 6;               // 0..7
  int wm = wave >> 2;                // 0..1
  int wn = wave & 3;                 // 0..3
  int m16 = lane & 15, quad = lane >> 4;

  const unsigned short* Ab = A + (size_t)tm * 256 * K;
  const unsigned short* Bb = B + (size_t)tn * 256 * K;

  int rowS = tid >> 3;
  int gcbS = (tid & 7) ^ (rowS & 7);
  int ldsWB = (tid & ~63) * 8;

  int sw = m16 & 7;
  int coff0 = (quad ^ sw) << 3;
  int coff1 = ((4 + quad) ^ sw) << 3;
  int aoff = (wm * 128 + m16) * 64;
  int boff = (wn * 64 + m16) * 64;

  f32x4 acc[8][4];
#pragma unroll
  for (int i = 0; i < 8; ++i)
#pragma unroll
    for (int j = 0; j < 4; ++j)
#pragma unroll
      for (int t = 0; t < 4; ++t) acc[i][j][t] = 0.0f;

  auto stageA = [&](int bufb, int t, int h) {
    int kt = k_begin + t * 64;
    unsigned short* dst = &As[bufb][0];
#pragma unroll
    for (int c = 2 * h; c < 2 * h + 2; ++c)
      async_cp16(Ab + (size_t)(c * 64 + rowS) * K + kt + gcbS * 8,
                 dst + c * 4096 + ldsWB);
  };
  auto stageB = [&](int bufb, int t, int h) {
    int kt = k_begin + t * 64;
    unsigned short* dst = &Bs[bufb][0];
#pragma unroll
    for (int c = 2 * h; c < 2 * h + 2; ++c)
      async_cp16(Bb + (size_t)(c * 64 + rowS) * K + kt + gcbS * 8,
                 dst + c * 4096 + ldsWB);
  };

  stageA(0, 0, 0); stageA(0, 0, 1);
  stageB(0, 0, 0); stageB(0, 0, 1);
  stageB(1, 1, 0); stageB(1, 1, 1);
  stageA(1, 1, 0);
  asm volatile("s_waitcnt vmcnt(6)" ::: "memory");
  __builtin_amdgcn_s_barrier();

  bf16x8 a[4][2], b0[2][2], b1[2][2];

  for (int t0 = 0; t0 < NT; t0 += 2) {
    int t1 = t0 + 1;
    bool notLast = (t0 + 2 < NT);
    unsigned short* A0 = &As[0][0];
    unsigned short* B0 = &Bs[0][0];
    unsigned short* A1 = &As[1][0];
    unsigned short* B1 = &Bs[1][0];

    // ---- p0 ----
#pragma unroll
    for (int i = 0; i < 4; ++i) {
      a[i][0] = *reinterpret_cast<const bf16x8*>(&A0[aoff + i * 1024 + coff0]);
      a[i][1] = *reinterpret_cast<const bf16x8*>(&A0[aoff + i * 1024 + coff1]);
    }
#pragma unroll
    for (int j = 0; j < 2; ++j) {
      b0[j][0] = *reinterpret_cast<const bf16x8*>(&B0[boff + j * 1024 + coff0]);
      b0[j][1] = *reinterpret_cast<const bf16x8*>(&B0[boff + j * 1024 + coff1]);
    }
    stageA(1, t1, 1);
    __builtin_amdgcn_s_barrier();
    asm volatile("s_waitcnt lgkmcnt(0)" ::: "memory");
    __builtin_amdgcn_sched_barrier(0);
    __builtin_amdgcn_s_setprio(1);
#pragma unroll
    for (int kk = 0; kk < 2; ++kk)
#pragma unroll
      for (int i = 0; i < 4; ++i)
#pragma unroll
        for (int j = 0; j < 2; ++j)
          acc[i][j] = __builtin_amdgcn_mfma_f32_16x16x32_bf16(
              a[i][kk], b0[j][kk], acc[i][j], 0, 0, 0);
    __builtin_amdgcn_s_setprio(0);
    __builtin_amdgcn_s_barrier();

    // ---- p1 ----
#pragma unroll
    for (int j = 0; j < 2; ++j) {
      b1[j][0] = *reinterpret_cast<const bf16x8*>(&B0[boff + (2 + j) * 1024 + coff0]);
      b1[j][1] = *reinterpret_cast<const bf16x8*>(&B0[boff + (2 + j) * 1024 + coff1]);
    }
    __builtin_amdgcn_s_barrier();
    asm volatile("s_waitcnt lgkmcnt(0)" ::: "memory");
    __builtin_amdgcn_sched_barrier(0);
    __builtin_amdgcn_s_setprio(1);
#pragma unroll
    for (int kk = 0; kk < 2; ++kk)
#pragma unroll
      for (int i = 0; i < 4; ++i)
#pragma unroll
        for (int j = 0; j < 2; ++j)
          acc[i][2 + j] = __builtin_amdgcn_mfma_f32_16x16x32_bf16(
              a[i][kk], b1[j][kk], acc[i][2 + j], 0, 0, 0);
    __builtin_amdgcn_s_setprio(0);
    __builtin_amdgcn_s_barrier();

    // ---- p2 ----
#pragma unroll
    for (int i = 0; i < 4; ++i) {
      a[i][0] = *reinterpret_cast<const bf16x8*>(&A0[aoff + (4 + i) * 1024 + coff0]);
      a[i][1] = *reinterpret_cast<const bf16x8*>(&A0[aoff + (4 + i) * 1024 + coff1]);
    }
    if (notLast) stageB(0, t0 + 2, 0);
    __builtin_amdgcn_s_barrier();
    asm volatile("s_waitcnt lgkmcnt(0)" ::: "memory");
    __builtin_amdgcn_sched_barrier(0);
    __builtin_amdgcn_s_setprio(1);
#pragma unroll
    for (int kk = 0; kk < 2; ++kk)
#pragma unroll
      for (int i = 0; i < 4; ++i)
#pragma unroll
        for (int j = 0; j < 2; ++j)
          acc[4 + i][2 + j] = __builtin_amdgcn_mfma_f32_16x16x32_bf16(
              a[i][kk], b1[j][kk], acc[4 + i][2 + j], 0, 0, 0);
    __builtin_amdgcn_s_setprio(0);
    __builtin_amdgcn_s_barrier();

    // ---- p3 ----
    if (notLast) stageB(0, t0 + 2, 1);
    __builtin_amdgcn_s_setprio(1);
#pragma unroll
    for (int kk = 0; kk < 2; ++kk)
#pragma unroll
      for (int i = 0; i < 4; ++i)
#pragma unroll
        for (int j = 0; j < 2; ++j)
          acc[4 + i][j] = __builtin_amdgcn_mfma_f32_16x16x32_bf16(
              a[i][kk], b0[j][kk], acc[4 + i][j], 0, 0, 0);
    __builtin_amdgcn_s_setprio(0);
    if (notLast) {
      asm volatile("s_waitcnt vmcnt(4)" ::: "memory");
    } else {
      asm volatile("s_waitcnt vmcnt(0)" ::: "memory");
    }
    __builtin_amdgcn_s_barrier();

    // ---- p4 ----
#pragma unroll
    for (int i = 0; i < 4; ++i) {
      a[i][0] = *reinterpret_cast<const bf16x8*>(&A1[aoff + i * 1024 + coff0]);
      a[i][1] = *reinterpret_cast<const bf16x8*>(&A1[aoff + i * 1024 + coff1]);
    }
#pragma unroll
    for (int j = 0; j < 2; ++j) {
      b0[j][0] = *reinterpret_cast<const bf16x8*>(&B1[boff + j * 1024 + coff0]);
      b0[j][1] = *reinterpret_cast<const bf16x8*>(&B1[boff + j * 1024 + coff1]);
    }
    if (notLast) stageA(0, t0 + 2, 0);
    __builtin_amdgcn_s_barrier();
    asm volatile("s_waitcnt lgkmcnt(0)" ::: "memory");
    __builtin_amdgcn_sched_barrier(0);
    __builtin_amdgcn_s_setprio(1);
#pragma unroll
    for (int kk = 0; kk < 2; ++kk)
#pragma unroll
      for (int i = 0; i < 4; ++i)
#pragma unroll
        for (int j = 0; j < 2; ++j)
          acc[i][j] = __builtin_amdgcn_mfma_f32_16x16x32_bf16(
              a[i][kk], b0[j][kk], acc[i][j], 0, 0, 0);
    __builtin_amdgcn_s_setprio(0);
    __builtin_amdgcn_s_barrier();

    // ---- p5 ----
#pragma unroll
    for (int j = 0; j < 2; ++j) {
      b1[j][0] = *reinterpret_cast<const bf16x8*>(&B1[boff + (2 + j) * 1024 + coff0]);
      b1[j][1] = *reinterpret_cast<const bf16x8*>(&B1[boff + (2 + j) * 1024 + coff1]);
    }
    if (notLast) stageA(0, t0 + 2, 1);
    __builtin_amdgcn_s_barrier();
    asm volatile("s_waitcnt lgkmcnt(0)" ::: "memory");
    __builtin_amdgcn_sched_barrier(0);
    __builtin_amdgcn_s_setprio(1);
#pragma unroll
    for (int kk = 0; kk < 2; ++kk)
#pragma unroll
      for (int i = 0; i < 4; ++i)
#pragma unroll
        for (int j = 0; j < 2; ++j)
          acc[i][2 + j] = __builtin_amdgcn_mfma_f32_16x16x32_bf16(
              a[i][kk], b1[j][kk], acc[i][2 + j], 0, 0, 0);
    __builtin_amdgcn_s_setprio(0);
    __builtin_amdgcn_s_barrier();

    // ---- p6 ----
#pragma unroll
    for (int i = 0; i < 4; ++i) {
      a[i][0] = *reinterpret_cast<const bf16x8*>(&A1[aoff + (4 + i) * 1024 + coff0]);
      a[i][1] = *reinterpret_cast<const bf16x8*>(&A1[aoff + (4 + i) * 1024 + coff1]);
    }
    if (notLast) stageB(1, t1 + 2, 0);
    __builtin_amdgcn_s_barrier();
    asm volatile("s_waitcnt lgkmcnt(0)" ::: "memory");
    __builtin_amdgcn_sched_barrier(0);
    __builtin_amdgcn_s_setprio(1);
#pragma unroll
    for (int kk = 0; kk < 2; ++kk)
#pragma unroll
      for (int i = 0; i < 4; ++i)
#pragma unroll
        for (int j = 0; j < 2; ++j)
          acc[4 + i][2 + j] = __builtin_amdgcn_mfma_f32_16x16x32_bf16(
              a[i][kk], b1[j][kk], acc[4 + i][2 + j], 0, 0, 0);
    __builtin_amdgcn_s_setprio(0);
    __builtin_amdgcn_s_barrier();

    // ---- p7 ----
    if (notLast) { stageB(1, t1 + 2, 1); stageA(1, t1 + 2, 0); }
    __builtin_amdgcn_s_setprio(1);
#pragma unroll
    for (int kk = 0; kk < 2; ++kk)
#pragma unroll
      for (int i = 0; i < 4; ++i)
#pragma unroll
        for (int j = 0; j < 2; ++j)
          acc[4 + i][j] = __builtin_amdgcn_mfma_f32_16x16x32_bf16(
              a[i][kk], b0[j][kk], acc[4 + i][j], 0, 0, 0);
    __builtin_amdgcn_s_setprio(0);
    if (notLast) {
      asm volatile("s_waitcnt vmcnt(6)" ::: "memory");
    }
    __builtin_amdgcn_s_barrier();
  }

  // ---------------- epilogue ----------------
  int rowB = tm * 256 + wm * 128;
  int colB = tn * 256 + wn * 64;
  if constexpr (EPI == 2) {
    if (colB < EE) {
#pragma unroll
      for (int mi = 0; mi < 8; ++mi)
#pragma unroll
        for (int nj = 0; nj < 4; ++nj) {
          int col = colB + nj * 16 + m16;
          int row0 = rowB + mi * 16 + quad * 4;
#pragma unroll
          for (int t4 = 0; t4 < 4; ++t4)
            auxF[(size_t)(row0 + t4) * EE + col] = acc[mi][nj][t4];
        }
    } else {
#pragma unroll
      for (int mi = 0; mi < 8; ++mi)
#pragma unroll
        for (int nj = 0; nj < 4; ++nj) {
          int cg = colB + nj * 16 + m16 - EE;
          int row0 = rowB + mi * 16 + quad * 4;
#pragma unroll
          for (int t4 = 0; t4 < 4; ++t4) {
            float v = acc[mi][nj][t4];
            float s = v / (1.0f + __expf(-v));
            auxB[(size_t)(row0 + t4) * EE + cg] = f2bf(s);
          }
        }
    }
  }
}

// ====== 128x128 8-phase BT-GEMM, NO split-K, direct store (out_proj) =======
// 256 threads = 4 waves (2Mx2N), per-wave 64x64. BK=64, dbuf LDS 64 KiB ->
// 2 blocks/CU. Same 8-phase counted-vmcnt schedule; half-tile = 2 staging
// calls. Direct coalesced f32 stores (no atomics, no pre-zero). R5: ~30us.
__global__ __launch_bounds__(256, 2) void gemm128p(
    const unsigned short* __restrict__ A,
    const unsigned short* __restrict__ B,
    float* __restrict__ C,
    int M, int N, int K, int tilesM) {
  __shared__ __align__(16) unsigned short As[2][8192];
  __shared__ __align__(16) unsigned short Bs[2][8192];

  int bid = blockIdx.x;
  int tnInner = bid & 7;
  int rest = bid >> 3;
  int tm = rest % tilesM;
  int tn = (rest / tilesM) * 8 + tnInner;

  int NT = K / 64;

  int tid = threadIdx.x;
  int lane = tid & 63;
  int wave = tid >> 6;
  int wm = wave >> 1;
  int wn = wave & 1;
  int m16 = lane & 15, quad = lane >> 4;

  const unsigned short* Ab = A + (size_t)tm * 128 * K;
  const unsigned short* Bb = B + (size_t)tn * 128 * K;

  int rowS = tid >> 3;
  int gcbS = (tid & 7) ^ (rowS & 7);
  int ldsWB = (tid & ~63) * 8;

  int sw = m16 & 7;
  int coff0 = (quad ^ sw) << 3;
  int coff1 = ((4 + quad) ^ sw) << 3;
  int aoff = (wm * 64 + m16) * 64;
  int boff = (wn * 64 + m16) * 64;

  f32x4 acc[4][4];
#pragma unroll
  for (int i = 0; i < 4; ++i)
#pragma unroll
    for (int j = 0; j < 4; ++j)
#pragma unroll
      for (int t = 0; t < 4; ++t) acc[i][j][t] = 0.0f;

  auto stageA = [&](int bufb, int t, int h) {
    int kt = t * 64;
    unsigned short* dst = &As[bufb][0];
#pragma unroll
    for (int c = 2 * h; c < 2 * h + 2; ++c)
      async_cp16(Ab + (size_t)(c * 32 + rowS) * K + kt + gcbS * 8,
                 dst + c * 2048 + ldsWB);
  };
  auto stageB = [&](int bufb, int t, int h) {
    int kt = t * 64;
    unsigned short* dst = &Bs[bufb][0];
#pragma unroll
    for (int c = 2 * h; c < 2 * h + 2; ++c)
      async_cp16(Bb + (size_t)(c * 32 + rowS) * K + kt + gcbS * 8,
                 dst + c * 2048 + ldsWB);
  };

  stageA(0, 0, 0); stageA(0, 0, 1);
  stageB(0, 0, 0); stageB(0, 0, 1);
  stageB(1, 1, 0); stageB(1, 1, 1);
  stageA(1, 1, 0);
  asm volatile("s_waitcnt vmcnt(6)" ::: "memory");
  __builtin_amdgcn_s_barrier();

  bf16x8 a[2][2], b0[2][2], b1[2][2];

  for (int t0 = 0; t0 < NT; t0 += 2) {
    int t1 = t0 + 1;
    bool notLast = (t0 + 2 < NT);
    unsigned short* A0 = &As[0][0];
    unsigned short* B0 = &Bs[0][0];
    unsigned short* A1 = &As[1][0];
    unsigned short* B1 = &Bs[1][0];

    // ---- p0 ----
#pragma unroll
    for (int i = 0; i < 2; ++i) {
      a[i][0] = *reinterpret_cast<const bf16x8*>(&A0[aoff + i * 1024 + coff0]);
      a[i][1] = *reinterpret_cast<const bf16x8*>(&A0[aoff + i * 1024 + coff1]);
    }
#pragma unroll
    for (int j = 0; j < 2; ++j) {
      b0[j][0] = *reinterpret_cast<const bf16x8*>(&B0[boff + j * 1024 + coff0]);
      b0[j][1] = *reinterpret_cast<const bf16x8*>(&B0[boff + j * 1024 + coff1]);
    }
    stageA(1, t1, 1);
    __builtin_amdgcn_s_barrier();
    asm volatile("s_waitcnt lgkmcnt(0)" ::: "memory");
    __builtin_amdgcn_sched_barrier(0);
    __builtin_amdgcn_s_setprio(1);
#pragma unroll
    for (int kk = 0; kk < 2; ++kk)
#pragma unroll
      for (int i = 0; i < 2; ++i)
#pragma unroll
        for (int j = 0; j < 2; ++j)
          acc[i][j] = __builtin_amdgcn_mfma_f32_16x16x32_bf16(
              a[i][kk], b0[j][kk], acc[i][j], 0, 0, 0);
    __builtin_amdgcn_s_setprio(0);
    __builtin_amdgcn_s_barrier();

    // ---- p1 ----
#pragma unroll
    for (int j = 0; j < 2; ++j) {
      b1[j][0] = *reinterpret_cast<const bf16x8*>(&B0[boff + (2 + j) * 1024 + coff0]);
      b1[j][1] = *reinterpret_cast<const bf16x8*>(&B0[boff + (2 + j) * 1024 + coff1]);
    }
    __builtin_amdgcn_s_barrier();
    asm volatile("s_waitcnt lgkmcnt(0)" ::: "memory");
    __builtin_amdgcn_sched_barrier(0);
    __builtin_amdgcn_s_setprio(1);
#pragma unroll
    for (int kk = 0; kk < 2; ++kk)
#pragma unroll
      for (int i = 0; i < 2; ++i)
#pragma unroll
        for (int j = 0; j < 2; ++j)
          acc[i][2 + j] = __builtin_amdgcn_mfma_f32_16x16x32_bf16(
              a[i][kk], b1[j][kk], acc[i][2 + j], 0, 0, 0);
    __builtin_amdgcn_s_setprio(0);
    __builtin_amdgcn_s_barrier();

    // ---- p2 ----
#pragma unroll
    for (int i = 0; i < 2; ++i) {
      a[i][0] = *reinterpret_cast<const bf16x8*>(&A0[aoff + (2 + i) * 1024 + coff0]);
      a[i][1] = *reinterpret_cast<const bf16x8*>(&A0[aoff + (2 + i) * 1024 + coff1]);
    }
    if (notLast) stageB(0, t0 + 2, 0);
    __builtin_amdgcn_s_barrier();
    asm volatile("s_waitcnt lgkmcnt(0)" ::: "memory");
    __builtin_amdgcn_sched_barrier(0);
    __builtin_amdgcn_s_setprio(1);
#pragma unroll
    for (int kk = 0; kk < 2; ++kk)
#pragma unroll
      for (int i = 0; i < 2; ++i)
#pragma unroll
        for (int j = 0; j < 2; ++j)
          acc[2 + i][2 + j] = __builtin_amdgcn_mfma_f32_16x16x32_bf16(
              a[i][kk], b1[j][kk], acc[2 + i][2 + j], 0, 0, 0);
    __builtin_amdgcn_s_setprio(0);
    __builtin_amdgcn_s_barrier();

    // ---- p3 ----
    if (notLast) stageB(0, t0 + 2, 1);
    __builtin_amdgcn_s_setprio(1);
#pragma unroll
    for (int kk = 0; kk < 2; ++kk)
#pragma unroll
      for (int i = 0; i < 2; ++i)
#pragma unroll
        for (int j = 0; j < 2; ++j)
          acc[2 + i][j] = __builtin_amdgcn_mfma_f32_16x16x32_bf16(
              a[i][kk], b0[j][kk], acc[2 + i][j], 0, 0, 0);
    __builtin_amdgcn_s_setprio(0);
    if (notLast) {
      asm volatile("s_waitcnt vmcnt(4)" ::: "memory");
    } else {
      asm volatile("s_waitcnt vmcnt(0)" ::: "memory");
    }
    __builtin_amdgcn_s_barrier();

    // ---- p4 ----
#pragma unroll
    for (int i = 0; i < 2; ++i) {
      a[i][0] = *reinterpret_cast<const bf16x8*>(&A1[aoff + i * 1024 + coff0]);
      a[i][1] = *reinterpret_cast<const bf16x8*>(&A1[aoff + i * 1024 + coff1]);
    }
#pragma unroll
    for (int j = 0; j < 2; ++j) {
      b0[j][0] = *reinterpret_cast<const bf16x8*>(&B1[boff + j * 1024 + coff0]);
      b0[j][1] = *reinterpret_cast<const bf16x8*>(&B1[boff + j * 1024 + coff1]);
    }
    if (notLast) stageA(0, t0 + 2, 0);
    __builtin_amdgcn_s_barrier();
    asm volatile("s_waitcnt lgkmcnt(0)" ::: "memory");
    __builtin_amdgcn_sched_barrier(0);
    __builtin_amdgcn_s_setprio(1);
#pragma unroll
    for (int kk = 0; kk < 2; ++kk)
#pragma unroll
      for (int i = 0; i < 2; ++i)
#pragma unroll
        for (int j = 0; j < 2; ++j)
          acc[i][j] = __builtin_amdgcn_mfma_f32_16x16x32_bf16(
              a[i][kk], b0[j][kk], acc[i][j], 0, 0, 0);
    __builtin_amdgcn_s_setprio(0);
    __builtin_amdgcn_s_barrier();

    // ---- p5 ----
#pragma unroll
    for (int j = 0; j < 2; ++j) {
      b1[j][0] = *reinterpret_cast<const bf16x8*>(&B1[boff + (2 + j) * 1024 + coff0]);
      b1[j][1] = *reinterpret_cast<const bf16x8*>(&B1[boff + (2 + j) * 1024 + coff1]);
    }
    if (notLast) stageA(0, t0 + 2, 1);
    __builtin_amdgcn_s_barrier();
    asm volatile("s_waitcnt lgkmcnt(0)" ::: "memory");
    __builtin_amdgcn_sched_barrier(0);
    __builtin_amdgcn_s_setprio(1);
#pragma unroll
    for (int kk = 0; kk < 2; ++kk)
#pragma unroll
      for (int i = 0; i < 2; ++i)
#pragma unroll
        for (int j = 0; j < 2; ++j)
          acc[i][2 + j] = __builtin_amdgcn_mfma_f32_16x16x32_bf16(
              a[i][kk], b1[j][kk], acc[i][2 + j], 0, 0, 0);
    __builtin_amdgcn_s_setprio(0);
    __builtin_amdgcn_s_barrier();

    // ---- p6 ----
#pragma unroll
    for (int i = 0; i < 2; ++i) {
      a[i][0] = *reinterpret_cast<const bf16x8*>(&A1[aoff + (2 + i) * 1024 + coff0]);
      a[i][1] = *reinterpret_cast<const bf16x8*>(&A1[aoff + (2 + i) * 1024 + coff1]);
    }
    if (notLast) stageB(1, t1 + 2, 0);
    __builtin_amdgcn_s_barrier();
    asm volatile("s_waitcnt lgkmcnt(0)" ::: "memory");
    __builtin_amdgcn_sched_barrier(0);
    __builtin_amdgcn_s_setprio(1);
#pragma unroll
    for (int kk = 0; kk < 2; ++kk)
#pragma unroll
      for (int i = 0; i < 2; ++i)
#pragma unroll
        for (int j = 0; j < 2; ++j)
          acc[2 + i][2 + j] = __builtin_amdgcn_mfma_f32_16x16x32_bf16(
              a[i][kk], b1[j][kk], acc[2 + i][2 + j], 0, 0, 0);
    __builtin_amdgcn_s_setprio(0);
    __builtin_amdgcn_s_barrier();

    // ---- p7 ----
    if (notLast) { stageB(1, t1 + 2, 1); stageA(1, t1 + 2, 0); }
    __builtin_amdgcn_s_setprio(1);
#pragma unroll
    for (int kk = 0; kk < 2; ++kk)
#pragma unroll
      for (int i = 0; i < 2; ++i)
#pragma unroll
        for (int j = 0; j < 2; ++j)
          acc[2 + i][j] = __builtin_amdgcn_mfma_f32_16x16x32_bf16(
              a[i][kk], b0[j][kk], acc[2 + i][j], 0, 0, 0);
    __builtin_amdgcn_s_setprio(0);
    if (notLast) {
      asm volatile("s_waitcnt vmcnt(6)" ::: "memory");
    }
    __builtin_amdgcn_s_barrier();
  }

  int rowB = tm * 128 + wm * 64;
  int colB = tn * 128 + wn * 64;
#pragma unroll
  for (int mi = 0; mi < 4; ++mi)
#pragma unroll
    for (int nj = 0; nj < 4; ++nj) {
      int col = colB + nj * 16 + m16;
      int row0 = rowB + mi * 16 + quad * 4;
#pragma unroll
      for (int t4 = 0; t4 < 4; ++t4)
        C[(size_t)(row0 + t4) * N + col] = acc[mi][nj][t4];
    }
}

// ---------- direct (no-LDS, no-barrier) BT-GEMM for small-K work ----------
// 256 threads = 4 waves; per block 64 rows x 128 cols; K-loop step 32, pure
// register pipeline (compiler prefetches — no syncs anywhere).
// EPI: 0 = direct f32 store
//      2 = per-slice partial slab: (C + blockIdx.y*M*N) direct store — NO
//          atomics (cross-XCD atomic RMW serialization, see out_proj lesson)
//      4 = bias[col] + softplus -> bf16 auxB (stride N), splitk must be 1
template <int EPI>
__global__ __launch_bounds__(256) void gemm_bt(
    const unsigned short* __restrict__ A,
    const unsigned short* __restrict__ B,
    float* __restrict__ C,
    int M, int N, int K, int tilesN, int splitk,
    const float* __restrict__ bias, unsigned short* __restrict__ auxB) {
  int bid = blockIdx.x;
  int groupSize = 8 * tilesN;
  int g = bid / groupSize, r = bid % groupSize;
  int tm = g * 8 + (r & 7);
  int tn = r >> 3;

  int Kslice = K / splitk;
  int k_begin = blockIdx.y * Kslice;
  int k_end = k_begin + Kslice;

  int tid = threadIdx.x;
  int wave = tid >> 6, lane = tid & 63;
  int wm = wave & 1, wn = wave >> 1;
  int m16 = lane & 15, quad = lane >> 4;
  int rowBase = tm * 64 + wm * 32;
  int colBase = tn * 128 + wn * 64;

  const unsigned short* a0p = A + (size_t)(rowBase + m16) * K + quad * 8;
  const unsigned short* a1p = A + (size_t)(rowBase + 16 + m16) * K + quad * 8;
  const unsigned short* bp[4];
  bool bok[4];
#pragma unroll
  for (int j = 0; j < 4; ++j) {
    int col = colBase + j * 16 + m16;
    bok[j] = (col < N);
    bp[j] = B + (size_t)(bok[j] ? col : 0) * K + quad * 8;
  }

  f32x4 acc[2][4];
#pragma unroll
  for (int i = 0; i < 2; ++i)
#pragma unroll
    for (int j = 0; j < 4; ++j)
#pragma unroll
      for (int t = 0; t < 4; ++t) acc[i][j][t] = 0.0f;

  bf16x8 zero8;
#pragma unroll
  for (int t = 0; t < 8; ++t) zero8[t] = (__bf16)0.0f;

  for (int k = k_begin; k < k_end; k += 32) {
    bf16x8 a0 = *reinterpret_cast<const bf16x8*>(a0p + k);
    bf16x8 a1 = *reinterpret_cast<const bf16x8*>(a1p + k);
    bf16x8 b[4];
#pragma unroll
    for (int j = 0; j < 4; ++j)
      b[j] = bok[j] ? *reinterpret_cast<const bf16x8*>(bp[j] + k) : zero8;
#pragma unroll
    for (int j = 0; j < 4; ++j) {
      acc[0][j] = __builtin_amdgcn_mfma_f32_16x16x32_bf16(a0, b[j], acc[0][j], 0, 0, 0);
      acc[1][j] = __builtin_amdgcn_mfma_f32_16x16x32_bf16(a1, b[j], acc[1][j], 0, 0, 0);
    }
  }

  float* Cs = C;
  if constexpr (EPI == 2) Cs = C + (size_t)blockIdx.y * M * N;
#pragma unroll
  for (int i = 0; i < 2; ++i)
#pragma unroll
    for (int j = 0; j < 4; ++j) {
      int col = colBase + j * 16 + m16;
      if (col >= N) continue;
      int row0 = rowBase + i * 16 + quad * 4;
      if constexpr (EPI == 4) {
        float bv = bias[col];
#pragma unroll
        for (int t = 0; t < 4; ++t)
          auxB[(size_t)(row0 + t) * N + col] =
              f2bf(softplus_fast(acc[i][j][t] + bv));
      } else {
#pragma unroll
        for (int t = 0; t < 4; ++t)
          Cs[(size_t)(row0 + t) * N + col] = acc[i][j][t];
      }
    }
}

// --------- reduce 8 x_proj partial slabs -> ssm f32 + dtin bf16 ---------
__global__ __launch_bounds__(256) void xreduce_k(
    const float* __restrict__ xp, float* __restrict__ ssm,
    unsigned short* __restrict__ dtin) {
  int i = blockIdx.x * 256 + threadIdx.x;   // i < LL*160
  float s = 0.0f;
#pragma unroll
  for (int k = 0; k < 8; ++k)
    s += xp[(size_t)k * (LL * 160) + i];
  ssm[i] = s;
  int l = i / 160, r = i - l * 160;
  if (r < 128) dtin[l * 128 + r] = f2bf(s);
}

// ------- depthwise causal conv (K=4) + bias + silu, register window -------
__global__ __launch_bounds__(256) void conv_silu_k(
    const float* __restrict__ projh, const float* __restrict__ cw,
    const float* __restrict__ cb, unsigned short* __restrict__ hb) {
  int e = blockIdx.x * 256 + threadIdx.x;
  int l0 = blockIdx.y * 16;
  float w0 = cw[e * 4 + 0], w1 = cw[e * 4 + 1];
  float w2 = cw[e * 4 + 2], w3 = cw[e * 4 + 3];
  float bias = cb[e];
  float xm3 = (l0 >= 3) ? projh[(size_t)(l0 - 3) * EE + e] : 0.0f;
  float xm2 = (l0 >= 2) ? projh[(size_t)(l0 - 2) * EE + e] : 0.0f;
  float xm1 = (l0 >= 1) ? projh[(size_t)(l0 - 1) * EE + e] : 0.0f;
#pragma unroll
  for (int t = 0; t < 16; ++t) {
    int l = l0 + t;
    float x0 = projh[(size_t)l * EE + e];
    float acc = bias + w0 * xm3 + w1 * xm2 + w2 * xm1 + w3 * x0;
    float s = acc / (1.0f + __expf(-acc));
    hb[(size_t)l * EE + e] = f2bf(s);
    xm3 = xm2; xm2 = xm1; xm1 = x0;
  }
}

// ================= chunked selective scan (16 states per thread) ===========
__global__ __launch_bounds__(256) void scan_partA(
    const unsigned short* __restrict__ dtb, const unsigned short* __restrict__ hb,
    const float* __restrict__ ssm, const float* __restrict__ A_log,
    float* __restrict__ P, float* __restrict__ S) {
  int e = blockIdx.y * 256 + threadIdx.x;
  int c = blockIdx.x;
  float Aa[16];
#pragma unroll
  for (int q = 0; q < 4; ++q) {
    float4 a = reinterpret_cast<const float4*>(&A_log[(size_t)e * NS])[q];
    Aa[q * 4 + 0] = -__expf(a.x) * 1.44269504f;
    Aa[q * 4 + 1] = -__expf(a.y) * 1.44269504f;
    Aa[q * 4 + 2] = -__expf(a.z) * 1.44269504f;
    Aa[q * 4 + 3] = -__expf(a.w) * 1.44269504f;
  }
  float s[16], p[16];
#pragma unroll
  for (int n = 0; n < 16; ++n) { s[n] = 0.0f; p[n] = 1.0f; }
  int l0 = c * CT;
#pragma unroll 2
  for (int t = 0; t < CT; ++t) {
    int l = l0 + t;
    size_t o = (size_t)l * EE + e;
    float dtv = bf2f(dtb[o]);
    float hv = bf2f(hb[o]);
    float Bv[16];
#pragma unroll
    for (int q = 0; q < 4; ++q)
      *reinterpret_cast<float4*>(&Bv[q * 4]) =
          reinterpret_cast<const float4*>(&ssm[(size_t)l * 160 + 128])[q];
    float z = dtv * hv;
#pragma unroll
    for (int n = 0; n < 16; ++n) {
      float dA = __builtin_amdgcn_exp2f(dtv * Aa[n]);
      s[n] = s[n] * dA + z * Bv[n];
      p[n] *= dA;
    }
  }
  size_t base = ((size_t)c * EE + e) * NS;
#pragma unroll
  for (int q = 0; q < 4; ++q) {
    reinterpret_cast<float4*>(&P[base])[q] = *reinterpret_cast<float4*>(&p[q * 4]);
    reinterpret_cast<float4*>(&S[base])[q] = *reinterpret_cast<float4*>(&s[q * 4]);
  }
}

// inter-chunk exclusive scan; depth-2 software prefetch (4 waves/CU only —
// latency-bound, so deeper prefetch hides L3)
__global__ __launch_bounds__(256) void scan_chunkB(
    const float* __restrict__ P, float* __restrict__ S) {
  int gidx = blockIdx.x * 256 + threadIdx.x;
  const size_t stride = (size_t)EE * NS;
  float s = 0.0f;
  float pv0 = P[gidx], sv0 = S[gidx];
  float pv1 = P[stride + gidx], sv1 = S[stride + gidx];
  for (int c = 0; c < NC; ++c) {
    float pn = 0.0f, sn = 0.0f;
    if (c + 2 < NC) {
      size_t i2 = (size_t)(c + 2) * stride + gidx;
      pn = P[i2];
      sn = S[i2];
    }
    float s_next = s * pv0 + sv0;
    S[(size_t)c * stride + gidx] = s;
    s = s_next;
    pv0 = pv1; sv0 = sv1; pv1 = pn; sv1 = sn;
  }
}

__global__ __launch_bounds__(256) void scan_partC(
    const unsigned short* __restrict__ dtb, const unsigned short* __restrict__ hb,
    const float* __restrict__ ssm, const float* __restrict__ A_log,
    const float* __restrict__ Dp, const unsigned short* __restrict__ sg,
    const float* __restrict__ Sinit, unsigned short* __restrict__ yb) {
  int e = blockIdx.y * 256 + threadIdx.x;
  int c = blockIdx.x;
  float Aa[16];
#pragma unroll
  for (int q = 0; q < 4; ++q) {
    float4 a = reinterpret_cast<const float4*>(&A_log[(size_t)e * NS])[q];
    Aa[q * 4 + 0] = -__expf(a.x) * 1.44269504f;
    Aa[q * 4 + 1] = -__expf(a.y) * 1.44269504f;
    Aa[q * 4 + 2] = -__expf(a.z) * 1.44269504f;
    Aa[q * 4 + 3] = -__expf(a.w) * 1.44269504f;
  }
  float Dv = Dp[e];
  float s[16];
  size_t base = ((size_t)c * EE + e) * NS;
#pragma unroll
  for (int q = 0; q < 4; ++q)
    *reinterpret_cast<float4*>(&s[q * 4]) =
        reinterpret_cast<const float4*>(&Sinit[base])[q];
  int l0 = c * CT;
#pragma unroll 2
  for (int t = 0; t < CT; ++t) {
    int l = l0 + t;
    size_t o = (size_t)l * EE + e;
    float dtv = bf2f(dtb[o]);
    float hv = bf2f(hb[o]);
    float Bv[16], Cv[16];
#pragma unroll
    for (int q = 0; q < 4; ++q) {
      *reinterpret_cast<float4*>(&Bv[q * 4]) =
          reinterpret_cast<const float4*>(&ssm[(size_t)l * 160 + 128])[q];
      *reinterpret_cast<float4*>(&Cv[q * 4]) =
          reinterpret_cast<const float4*>(&ssm[(size_t)l * 160 + 144])[q];
    }
    float z = dtv * hv;
    float y = 0.0f;
#pragma unroll
    for (int n = 0; n < 16; ++n) {
      float dA = __builtin_amdgcn_exp2f(dtv * Aa[n]);
      s[n] = s[n] * dA + z * Bv[n];
      y += s[n] * Cv[n];
    }
    float gv = bf2f(sg[o]);  // pre-activated silu(gate)
    float yv = (y + hv * Dv) * gv;
    yb[o] = f2bf(yv);
  }
}

extern "C" void kernel_launch(void* const* d_in, const int* in_sizes, int n_in,
                              void* d_out, int out_size, void* d_ws, size_t ws_size,
                              hipStream_t stream) {
  const float* hs   = (const float*)d_in[0];
  const float* w1   = (const float*)d_in[1];
  const float* cw   = (const float*)d_in[2];
  const float* cb   = (const float*)d_in[3];
  const float* xw   = (const float*)d_in[4];
  const float* dtw  = (const float*)d_in[5];
  const float* dtb  = (const float*)d_in[6];
  const float* Alog = (const float*)d_in[7];
  const float* Dp   = (const float*)d_in[8];
  const float* ow   = (const float*)d_in[9];
  float* out = (float*)d_out;

  char* ws = (char*)d_ws;
  size_t off = 0;
  auto alloc = [&](size_t b) {
    char* p = ws + off;
    off += (b + 255) & ~(size_t)255;
    return p;
  };
  float* projh = (float*)alloc((size_t)LL * EE * 4);                 // 33.5 MB
  unsigned short* sg  = (unsigned short*)alloc((size_t)LL * EE * 2); // 16.8 MB
  unsigned short* hb  = (unsigned short*)alloc((size_t)LL * EE * 2); // 16.8 MB
  unsigned short* dtb_buf = (unsigned short*)alloc((size_t)LL * EE * 2); // 16.8 MB
  unsigned short* w1b = (unsigned short*)alloc((size_t)2 * EE * HH * 2); // 33.5 MB
  unsigned short* hsb = (unsigned short*)alloc((size_t)LL * HH * 2);
  unsigned short* yb  = (unsigned short*)alloc((size_t)LL * EE * 2);
  unsigned short* owb = (unsigned short*)alloc((size_t)HH * EE * 2);
  unsigned short* xwb = (unsigned short*)alloc((size_t)160 * EE * 2);
  float* ssm = (float*)alloc((size_t)LL * 160 * 4);
  unsigned short* dtin = (unsigned short*)alloc((size_t)LL * RR * 2);
  unsigned short* dtwb = (unsigned short*)alloc((size_t)EE * RR * 2);
  float* Pbuf = (float*)alloc((size_t)NC * EE * NS * 4);             // 16.8 MB
  float* Sbuf = (float*)alloc((size_t)NC * EE * NS * 4);             // 16.8 MB
  // x_proj partial slabs (8 x 2048 x 160 f32 = 10.5 MB) live in d_out, which
  // is dead until the final out_proj overwrites it entirely.
  float* xpart = out;

  // 0) fused prep: 5 input casts in ONE launch
  prep_k<<<P_C4 / 256, 256, 0, stream>>>(hs, hsb, w1, w1b, xw, xwb, dtw, dtwb,
                                         ow, owb);

  // 1) proj = hs @ in_proj_w^T [2048, 8192]; 256^2 8-phase counted-vmcnt.
  //    epilogue: h -> projh f32, gate -> silu -> sg bf16   (~78us measured)
  {
    int tilesM = LL / 256;          // 8
    int tilesN = (2 * EE) / 256;    // 32  -> 256 blocks, 1/CU
    gemm256<2><<<dim3(tilesM * tilesN, 1), 512, 0, stream>>>(
        hsb, w1b, nullptr, LL, 2 * EE, HH, tilesM, 1, projh, sg);
  }
  // 2) causal depthwise conv + silu -> h (bf16)
  conv_silu_k<<<dim3(EE / 256, LL / 16), 256, 0, stream>>>(projh, cw, cb, hb);
  // 3) ssm partials = h @ x_proj_w^T [2048, 160] k=4096, split-K=8 into
  //    per-slice slabs (no atomics)
  {
    int tilesN = (160 + 127) / 128, tilesM = LL / 64;
    gemm_bt<2><<<dim3(tilesM * tilesN, 8), 256, 0, stream>>>(
        hb, xwb, xpart, LL, 160, EE, tilesN, 8, nullptr, nullptr);
  }
  // 4) reduce slabs -> ssm f32; emit dt slice as bf16 (absorbs dtcast)
  xreduce_k<<<LL * 160 / 256, 256, 0, stream>>>(xpart, ssm, dtin);
  // 5) dt = softplus(dtin @ dt_proj_w^T + dtb) -> bf16  [2048,4096] k=128.
  //    Direct-register gemm_bt: K=128 is 4 unrolled steps, zero barriers —
  //    the LDS-staged version paid 2 full vmcnt(0) drains for 2 K-iters.
  {
    int tilesN = EE / 128, tilesM = LL / 64;   // 32 x 32 -> 1024 blocks
    gemm_bt<4><<<dim3(tilesM * tilesN, 1), 256, 0, stream>>>(
        dtin, dtwb, nullptr, LL, EE, RR, tilesN, 1, dtb, dtb_buf);
  }
  // 6) chunked selective scan + gating -> y (bf16)
  scan_partA<<<dim3(NC, EE / 256), 256, 0, stream>>>(dtb_buf, hb, ssm, Alog,
                                                     Pbuf, Sbuf);
  scan_chunkB<<<EE * NS / 256, 256, 0, stream>>>(Pbuf, Sbuf);
  scan_partC<<<dim3(NC, EE / 256), 256, 0, stream>>>(dtb_buf, hb, ssm, Alog, Dp,
                                                     sg, Sbuf, yb);
  // 7) out = y @ out_proj_w^T [2048, 2048] k=4096; 128^2 8-phase, no split-K,
  //    direct stores (overwrites the xpart scratch completely)
  {
    int tilesM = LL / 128, tilesN = HH / 128;  // 16 x 16 = 256
    gemm128p<<<dim3(tilesM * tilesN, 1), 256, 0, stream>>>(
        yb, owb, out, LL, HH, EE, tilesM);
  }
}

// Round 8
// 395.737 us; speedup vs baseline: 1.0288x; 1.0288x over previous
//
#include <hip/hip_runtime.h>

#define LL 2048
#define HH 2048
#define EE 4096
#define NS 16
#define RR 128
#define CT 32            // chunk timesteps
#define NC (LL / CT)     // 64 chunks

typedef __bf16 bf16x8 __attribute__((ext_vector_type(8)));
typedef float f32x4 __attribute__((ext_vector_type(4)));

__device__ __forceinline__ unsigned short f2bf(float f) {
  union { float f; unsigned int u; } v; v.f = f;
  unsigned int r = v.u + 0x7fffu + ((v.u >> 16) & 1u);
  return (unsigned short)(r >> 16);
}

__device__ __forceinline__ float bf2f(unsigned short u) {
  union { unsigned int i; float f; } v;
  v.i = ((unsigned int)u) << 16;
  return v.f;
}

// softplus via native transcendentals only (NO libm log1pf — non-inline ocml
// call forces VGPR save/restore in high-pressure epilogues)
__device__ __forceinline__ float softplus_fast(float x) {
  if (x > 20.0f) return x;
  float e = __builtin_amdgcn_exp2f(1.44269504f * x);
  return 0.69314718f * __builtin_amdgcn_logf(1.0f + e);
}

__device__ __forceinline__ void async_cp16(const unsigned short* g,
                                           unsigned short* l) {
  __builtin_amdgcn_global_load_lds(
      (const __attribute__((address_space(1))) unsigned int*)g,
      (__attribute__((address_space(3))) unsigned int*)l, 16, 0, 0);
}

// ============ fused prep: 5 bf16 casts + 1 zero fill, ONE launch ==========
// (out not zeroed: out_proj stores directly.)
#define P_C0 (LL * HH / 4)               // hs -> hsb
#define P_C1 (P_C0 + 2 * EE * HH / 4)    // w1 -> w1b
#define P_C2 (P_C1 + 160 * EE / 4)       // xw -> xwb
#define P_C3 (P_C2 + EE * RR / 4)        // dtw -> dtwb
#define P_C4 (P_C3 + HH * EE / 4)        // ow -> owb
#define P_C5 (P_C4 + LL * 160 / 4)       // zero ssm

__global__ __launch_bounds__(256) void prep_k(
    const float* __restrict__ hs, unsigned short* __restrict__ hsb,
    const float* __restrict__ w1, unsigned short* __restrict__ w1b,
    const float* __restrict__ xw, unsigned short* __restrict__ xwb,
    const float* __restrict__ dtw, unsigned short* __restrict__ dtwb,
    const float* __restrict__ ow, unsigned short* __restrict__ owb,
    float* __restrict__ ssm) {
  int i = blockIdx.x * 256 + threadIdx.x;
  const float* src;
  unsigned short* dst;
  int k;
  if (i < P_C0)      { src = hs;  dst = hsb;  k = i; }
  else if (i < P_C1) { src = w1;  dst = w1b;  k = i - P_C0; }
  else if (i < P_C2) { src = xw;  dst = xwb;  k = i - P_C1; }
  else if (i < P_C3) { src = dtw; dst = dtwb; k = i - P_C2; }
  else if (i < P_C4) { src = ow;  dst = owb;  k = i - P_C3; }
  else {
    float4 z; z.x = z.y = z.z = z.w = 0.0f;
    reinterpret_cast<float4*>(ssm)[i - P_C4] = z;
    return;
  }
  float4 v = reinterpret_cast<const float4*>(src)[k];
  ushort4 o;
  o.x = f2bf(v.x); o.y = f2bf(v.y); o.z = f2bf(v.z); o.w = f2bf(v.w);
  reinterpret_cast<ushort4*>(dst)[k] = o;
}

// ============= 256x256 8-phase BT-GEMM (proven: in_proj 75-78us) ===========
// 512 threads = 8 waves (2Mx4N), per-wave 128x64. BK=64, dbuf LDS 128 KiB.
// 8 phases / 2 K-tiles; counted vmcnt(4)/vmcnt(6); kk-outer MFMA (dep dist 8).
// NOTE: atomic split-K epilogue measured ~95us for out_proj (cross-XCD atomic
// RMW serialization) — never split-K this kernel with atomics.
// EPI: 2 = in_proj (cols<EE -> f32 auxF; cols>=EE -> silu bf16 auxB)
template <int EPI>
__global__ __launch_bounds__(512, 2) void gemm256(
    const unsigned short* __restrict__ A,
    const unsigned short* __restrict__ B,
    float* __restrict__ C,
    int M, int N, int K, int tilesM, int splitk,
    float* __restrict__ auxF, unsigned short* __restrict__ auxB) {
  __shared__ __align__(16) unsigned short As[2][16384];
  __shared__ __align__(16) unsigned short Bs[2][16384];

  int bid = blockIdx.x;
  int tnInner = bid & 7;             // XCD-locality
  int rest = bid >> 3;
  int tm = rest % tilesM;
  int tn = (rest / tilesM) * 8 + tnInner;

  int Kslice = K / splitk;
  int k_begin = blockIdx.y * Kslice;
  int NT = Kslice / 64;              // even, >= 2

  int tid = threadIdx.x;
  int lane = tid & 63;
  int wave = tid >> 6;               // 0..7
  int wm = wave >> 2;                // 0..1
  int wn = wave & 3;                 // 0..3
  int m16 = lane & 15, quad = lane >> 4;

  const unsigned short* Ab = A + (size_t)tm * 256 * K;
  const unsigned short* Bb = B + (size_t)tn * 256 * K;

  int rowS = tid >> 3;
  int gcbS = (tid & 7) ^ (rowS & 7);
  int ldsWB = (tid & ~63) * 8;

  int sw = m16 & 7;
  int coff0 = (quad ^ sw) << 3;
  int coff1 = ((4 + quad) ^ sw) << 3;
  int aoff = (wm * 128 + m16) * 64;
  int boff = (wn * 64 + m16) * 64;

  f32x4 acc[8][4];
#pragma unroll
  for (int i = 0; i < 8; ++i)
#pragma unroll
    for (int j = 0; j < 4; ++j)
#pragma unroll
      for (int t = 0; t < 4; ++t) acc[i][j][t] = 0.0f;

  auto stageA = [&](int bufb, int t, int h) {
    int kt = k_begin + t * 64;
    unsigned short* dst = &As[bufb][0];
#pragma unroll
    for (int c = 2 * h; c < 2 * h + 2; ++c)
      async_cp16(Ab + (size_t)(c * 64 + rowS) * K + kt + gcbS * 8,
                 dst + c * 4096 + ldsWB);
  };
  auto stageB = [&](int bufb, int t, int h) {
    int kt = k_begin + t * 64;
    unsigned short* dst = &Bs[bufb][0];
#pragma unroll
    for (int c = 2 * h; c < 2 * h + 2; ++c)
      async_cp16(Bb + (size_t)(c * 64 + rowS) * K + kt + gcbS * 8,
                 dst + c * 4096 + ldsWB);
  };

  stageA(0, 0, 0); stageA(0, 0, 1);
  stageB(0, 0, 0); stageB(0, 0, 1);
  stageB(1, 1, 0); stageB(1, 1, 1);
  stageA(1, 1, 0);
  asm volatile("s_waitcnt vmcnt(6)" ::: "memory");
  __builtin_amdgcn_s_barrier();

  bf16x8 a[4][2], b0[2][2], b1[2][2];

  for (int t0 = 0; t0 < NT; t0 += 2) {
    int t1 = t0 + 1;
    bool notLast = (t0 + 2 < NT);
    unsigned short* A0 = &As[0][0];
    unsigned short* B0 = &Bs[0][0];
    unsigned short* A1 = &As[1][0];
    unsigned short* B1 = &Bs[1][0];

    // ---- p0 ----
#pragma unroll
    for (int i = 0; i < 4; ++i) {
      a[i][0] = *reinterpret_cast<const bf16x8*>(&A0[aoff + i * 1024 + coff0]);
      a[i][1] = *reinterpret_cast<const bf16x8*>(&A0[aoff + i * 1024 + coff1]);
    }
#pragma unroll
    for (int j = 0; j < 2; ++j) {
      b0[j][0] = *reinterpret_cast<const bf16x8*>(&B0[boff + j * 1024 + coff0]);
      b0[j][1] = *reinterpret_cast<const bf16x8*>(&B0[boff + j * 1024 + coff1]);
    }
    stageA(1, t1, 1);
    __builtin_amdgcn_s_barrier();
    asm volatile("s_waitcnt lgkmcnt(0)" ::: "memory");
    __builtin_amdgcn_sched_barrier(0);
    __builtin_amdgcn_s_setprio(1);
#pragma unroll
    for (int kk = 0; kk < 2; ++kk)
#pragma unroll
      for (int i = 0; i < 4; ++i)
#pragma unroll
        for (int j = 0; j < 2; ++j)
          acc[i][j] = __builtin_amdgcn_mfma_f32_16x16x32_bf16(
              a[i][kk], b0[j][kk], acc[i][j], 0, 0, 0);
    __builtin_amdgcn_s_setprio(0);
    __builtin_amdgcn_s_barrier();

    // ---- p1 ----
#pragma unroll
    for (int j = 0; j < 2; ++j) {
      b1[j][0] = *reinterpret_cast<const bf16x8*>(&B0[boff + (2 + j) * 1024 + coff0]);
      b1[j][1] = *reinterpret_cast<const bf16x8*>(&B0[boff + (2 + j) * 1024 + coff1]);
    }
    __builtin_amdgcn_s_barrier();
    asm volatile("s_waitcnt lgkmcnt(0)" ::: "memory");
    __builtin_amdgcn_sched_barrier(0);
    __builtin_amdgcn_s_setprio(1);
#pragma unroll
    for (int kk = 0; kk < 2; ++kk)
#pragma unroll
      for (int i = 0; i < 4; ++i)
#pragma unroll
        for (int j = 0; j < 2; ++j)
          acc[i][2 + j] = __builtin_amdgcn_mfma_f32_16x16x32_bf16(
              a[i][kk], b1[j][kk], acc[i][2 + j], 0, 0, 0);
    __builtin_amdgcn_s_setprio(0);
    __builtin_amdgcn_s_barrier();

    // ---- p2 ----
#pragma unroll
    for (int i = 0; i < 4; ++i) {
      a[i][0] = *reinterpret_cast<const bf16x8*>(&A0[aoff + (4 + i) * 1024 + coff0]);
      a[i][1] = *reinterpret_cast<const bf16x8*>(&A0[aoff + (4 + i) * 1024 + coff1]);
    }
    if (notLast) stageB(0, t0 + 2, 0);
    __builtin_amdgcn_s_barrier();
    asm volatile("s_waitcnt lgkmcnt(0)" ::: "memory");
    __builtin_amdgcn_sched_barrier(0);
    __builtin_amdgcn_s_setprio(1);
#pragma unroll
    for (int kk = 0; kk < 2; ++kk)
#pragma unroll
      for (int i = 0; i < 4; ++i)
#pragma unroll
        for (int j = 0; j < 2; ++j)
          acc[4 + i][2 + j] = __builtin_amdgcn_mfma_f32_16x16x32_bf16(
              a[i][kk], b1[j][kk], acc[4 + i][2 + j], 0, 0, 0);
    __builtin_amdgcn_s_setprio(0);
    __builtin_amdgcn_s_barrier();

    // ---- p3 ----
    if (notLast) stageB(0, t0 + 2, 1);
    __builtin_amdgcn_s_setprio(1);
#pragma unroll
    for (int kk = 0; kk < 2; ++kk)
#pragma unroll
      for (int i = 0; i < 4; ++i)
#pragma unroll
        for (int j = 0; j < 2; ++j)
          acc[4 + i][j] = __builtin_amdgcn_mfma_f32_16x16x32_bf16(
              a[i][kk], b0[j][kk], acc[4 + i][j], 0, 0, 0);
    __builtin_amdgcn_s_setprio(0);
    if (notLast) {
      asm volatile("s_waitcnt vmcnt(4)" ::: "memory");
    } else {
      asm volatile("s_waitcnt vmcnt(0)" ::: "memory");
    }
    __builtin_amdgcn_s_barrier();

    // ---- p4 ----
#pragma unroll
    for (int i = 0; i < 4; ++i) {
      a[i][0] = *reinterpret_cast<const bf16x8*>(&A1[aoff + i * 1024 + coff0]);
      a[i][1] = *reinterpret_cast<const bf16x8*>(&A1[aoff + i * 1024 + coff1]);
    }
#pragma unroll
    for (int j = 0; j < 2; ++j) {
      b0[j][0] = *reinterpret_cast<const bf16x8*>(&B1[boff + j * 1024 + coff0]);
      b0[j][1] = *reinterpret_cast<const bf16x8*>(&B1[boff + j * 1024 + coff1]);
    }
    if (notLast) stageA(0, t0 + 2, 0);
    __builtin_amdgcn_s_barrier();
    asm volatile("s_waitcnt lgkmcnt(0)" ::: "memory");
    __builtin_amdgcn_sched_barrier(0);
    __builtin_amdgcn_s_setprio(1);
#pragma unroll
    for (int kk = 0; kk < 2; ++kk)
#pragma unroll
      for (int i = 0; i < 4; ++i)
#pragma unroll
        for (int j = 0; j < 2; ++j)
          acc[i][j] = __builtin_amdgcn_mfma_f32_16x16x32_bf16(
              a[i][kk], b0[j][kk], acc[i][j], 0, 0, 0);
    __builtin_amdgcn_s_setprio(0);
    __builtin_amdgcn_s_barrier();

    // ---- p5 ----
#pragma unroll
    for (int j = 0; j < 2; ++j) {
      b1[j][0] = *reinterpret_cast<const bf16x8*>(&B1[boff + (2 + j) * 1024 + coff0]);
      b1[j][1] = *reinterpret_cast<const bf16x8*>(&B1[boff + (2 + j) * 1024 + coff1]);
    }
    if (notLast) stageA(0, t0 + 2, 1);
    __builtin_amdgcn_s_barrier();
    asm volatile("s_waitcnt lgkmcnt(0)" ::: "memory");
    __builtin_amdgcn_sched_barrier(0);
    __builtin_amdgcn_s_setprio(1);
#pragma unroll
    for (int kk = 0; kk < 2; ++kk)
#pragma unroll
      for (int i = 0; i < 4; ++i)
#pragma unroll
        for (int j = 0; j < 2; ++j)
          acc[i][2 + j] = __builtin_amdgcn_mfma_f32_16x16x32_bf16(
              a[i][kk], b1[j][kk], acc[i][2 + j], 0, 0, 0);
    __builtin_amdgcn_s_setprio(0);
    __builtin_amdgcn_s_barrier();

    // ---- p6 ----
#pragma unroll
    for (int i = 0; i < 4; ++i) {
      a[i][0] = *reinterpret_cast<const bf16x8*>(&A1[aoff + (4 + i) * 1024 + coff0]);
      a[i][1] = *reinterpret_cast<const bf16x8*>(&A1[aoff + (4 + i) * 1024 + coff1]);
    }
    if (notLast) stageB(1, t1 + 2, 0);
    __builtin_amdgcn_s_barrier();
    asm volatile("s_waitcnt lgkmcnt(0)" ::: "memory");
    __builtin_amdgcn_sched_barrier(0);
    __builtin_amdgcn_s_setprio(1);
#pragma unroll
    for (int kk = 0; kk < 2; ++kk)
#pragma unroll
      for (int i = 0; i < 4; ++i)
#pragma unroll
        for (int j = 0; j < 2; ++j)
          acc[4 + i][2 + j] = __builtin_amdgcn_mfma_f32_16x16x32_bf16(
              a[i][kk], b1[j][kk], acc[4 + i][2 + j], 0, 0, 0);
    __builtin_amdgcn_s_setprio(0);
    __builtin_amdgcn_s_barrier();

    // ---- p7 ----
    if (notLast) { stageB(1, t1 + 2, 1); stageA(1, t1 + 2, 0); }
    __builtin_amdgcn_s_setprio(1);
#pragma unroll
    for (int kk = 0; kk < 2; ++kk)
#pragma unroll
      for (int i = 0; i < 4; ++i)
#pragma unroll
        for (int j = 0; j < 2; ++j)
          acc[4 + i][j] = __builtin_amdgcn_mfma_f32_16x16x32_bf16(
              a[i][kk], b0[j][kk], acc[4 + i][j], 0, 0, 0);
    __builtin_amdgcn_s_setprio(0);
    if (notLast) {
      asm volatile("s_waitcnt vmcnt(6)" ::: "memory");
    }
    __builtin_amdgcn_s_barrier();
  }

  // ---------------- epilogue ----------------
  int rowB = tm * 256 + wm * 128;
  int colB = tn * 256 + wn * 64;
  if constexpr (EPI == 2) {
    if (colB < EE) {
#pragma unroll
      for (int mi = 0; mi < 8; ++mi)
#pragma unroll
        for (int nj = 0; nj < 4; ++nj) {
          int col = colB + nj * 16 + m16;
          int row0 = rowB + mi * 16 + quad * 4;
#pragma unroll
          for (int t4 = 0; t4 < 4; ++t4)
            auxF[(size_t)(row0 + t4) * EE + col] = acc[mi][nj][t4];
        }
    } else {
#pragma unroll
      for (int mi = 0; mi < 8; ++mi)
#pragma unroll
        for (int nj = 0; nj < 4; ++nj) {
          int cg = colB + nj * 16 + m16 - EE;
          int row0 = rowB + mi * 16 + quad * 4;
#pragma unroll
          for (int t4 = 0; t4 < 4; ++t4) {
            float v = acc[mi][nj][t4];
            float s = v / (1.0f + __expf(-v));
            auxB[(size_t)(row0 + t4) * EE + cg] = f2bf(s);
          }
        }
    }
  }
}

// ====== 128x128 8-phase BT-GEMM, NO split-K, direct store (out_proj) =======
// 256 threads = 4 waves (2Mx2N), per-wave 64x64. BK=64, dbuf LDS 64 KiB ->
// 2 blocks/CU. Same 8-phase counted-vmcnt schedule; half-tile = 2 staging
// calls. Direct coalesced f32 stores (no atomics, no pre-zero). R5: ~30us.
__global__ __launch_bounds__(256, 2) void gemm128p(
    const unsigned short* __restrict__ A,
    const unsigned short* __restrict__ B,
    float* __restrict__ C,
    int M, int N, int K, int tilesM) {
  __shared__ __align__(16) unsigned short As[2][8192];
  __shared__ __align__(16) unsigned short Bs[2][8192];

  int bid = blockIdx.x;
  int tnInner = bid & 7;
  int rest = bid >> 3;
  int tm = rest % tilesM;
  int tn = (rest / tilesM) * 8 + tnInner;

  int NT = K / 64;

  int tid = threadIdx.x;
  int lane = tid & 63;
  int wave = tid >> 6;
  int wm = wave >> 1;
  int wn = wave & 1;
  int m16 = lane & 15, quad = lane >> 4;

  const unsigned short* Ab = A + (size_t)tm * 128 * K;
  const unsigned short* Bb = B + (size_t)tn * 128 * K;

  int rowS = tid >> 3;
  int gcbS = (tid & 7) ^ (rowS & 7);
  int ldsWB = (tid & ~63) * 8;

  int sw = m16 & 7;
  int coff0 = (quad ^ sw) << 3;
  int coff1 = ((4 + quad) ^ sw) << 3;
  int aoff = (wm * 64 + m16) * 64;
  int boff = (wn * 64 + m16) * 64;

  f32x4 acc[4][4];
#pragma unroll
  for (int i = 0; i < 4; ++i)
#pragma unroll
    for (int j = 0; j < 4; ++j)
#pragma unroll
      for (int t = 0; t < 4; ++t) acc[i][j][t] = 0.0f;

  auto stageA = [&](int bufb, int t, int h) {
    int kt = t * 64;
    unsigned short* dst = &As[bufb][0];
#pragma unroll
    for (int c = 2 * h; c < 2 * h + 2; ++c)
      async_cp16(Ab + (size_t)(c * 32 + rowS) * K + kt + gcbS * 8,
                 dst + c * 2048 + ldsWB);
  };
  auto stageB = [&](int bufb, int t, int h) {
    int kt = t * 64;
    unsigned short* dst = &Bs[bufb][0];
#pragma unroll
    for (int c = 2 * h; c < 2 * h + 2; ++c)
      async_cp16(Bb + (size_t)(c * 32 + rowS) * K + kt + gcbS * 8,
                 dst + c * 2048 + ldsWB);
  };

  stageA(0, 0, 0); stageA(0, 0, 1);
  stageB(0, 0, 0); stageB(0, 0, 1);
  stageB(1, 1, 0); stageB(1, 1, 1);
  stageA(1, 1, 0);
  asm volatile("s_waitcnt vmcnt(6)" ::: "memory");
  __builtin_amdgcn_s_barrier();

  bf16x8 a[2][2], b0[2][2], b1[2][2];

  for (int t0 = 0; t0 < NT; t0 += 2) {
    int t1 = t0 + 1;
    bool notLast = (t0 + 2 < NT);
    unsigned short* A0 = &As[0][0];
    unsigned short* B0 = &Bs[0][0];
    unsigned short* A1 = &As[1][0];
    unsigned short* B1 = &Bs[1][0];

    // ---- p0 ----
#pragma unroll
    for (int i = 0; i < 2; ++i) {
      a[i][0] = *reinterpret_cast<const bf16x8*>(&A0[aoff + i * 1024 + coff0]);
      a[i][1] = *reinterpret_cast<const bf16x8*>(&A0[aoff + i * 1024 + coff1]);
    }
#pragma unroll
    for (int j = 0; j < 2; ++j) {
      b0[j][0] = *reinterpret_cast<const bf16x8*>(&B0[boff + j * 1024 + coff0]);
      b0[j][1] = *reinterpret_cast<const bf16x8*>(&B0[boff + j * 1024 + coff1]);
    }
    stageA(1, t1, 1);
    __builtin_amdgcn_s_barrier();
    asm volatile("s_waitcnt lgkmcnt(0)" ::: "memory");
    __builtin_amdgcn_sched_barrier(0);
    __builtin_amdgcn_s_setprio(1);
#pragma unroll
    for (int kk = 0; kk < 2; ++kk)
#pragma unroll
      for (int i = 0; i < 2; ++i)
#pragma unroll
        for (int j = 0; j < 2; ++j)
          acc[i][j] = __builtin_amdgcn_mfma_f32_16x16x32_bf16(
              a[i][kk], b0[j][kk], acc[i][j], 0, 0, 0);
    __builtin_amdgcn_s_setprio(0);
    __builtin_amdgcn_s_barrier();

    // ---- p1 ----
#pragma unroll
    for (int j = 0; j < 2; ++j) {
      b1[j][0] = *reinterpret_cast<const bf16x8*>(&B0[boff + (2 + j) * 1024 + coff0]);
      b1[j][1] = *reinterpret_cast<const bf16x8*>(&B0[boff + (2 + j) * 1024 + coff1]);
    }
    __builtin_amdgcn_s_barrier();
    asm volatile("s_waitcnt lgkmcnt(0)" ::: "memory");
    __builtin_amdgcn_sched_barrier(0);
    __builtin_amdgcn_s_setprio(1);
#pragma unroll
    for (int kk = 0; kk < 2; ++kk)
#pragma unroll
      for (int i = 0; i < 2; ++i)
#pragma unroll
        for (int j = 0; j < 2; ++j)
          acc[i][2 + j] = __builtin_amdgcn_mfma_f32_16x16x32_bf16(
              a[i][kk], b1[j][kk], acc[i][2 + j], 0, 0, 0);
    __builtin_amdgcn_s_setprio(0);
    __builtin_amdgcn_s_barrier();

    // ---- p2 ----
#pragma unroll
    for (int i = 0; i < 2; ++i) {
      a[i][0] = *reinterpret_cast<const bf16x8*>(&A0[aoff + (2 + i) * 1024 + coff0]);
      a[i][1] = *reinterpret_cast<const bf16x8*>(&A0[aoff + (2 + i) * 1024 + coff1]);
    }
    if (notLast) stageB(0, t0 + 2, 0);
    __builtin_amdgcn_s_barrier();
    asm volatile("s_waitcnt lgkmcnt(0)" ::: "memory");
    __builtin_amdgcn_sched_barrier(0);
    __builtin_amdgcn_s_setprio(1);
#pragma unroll
    for (int kk = 0; kk < 2; ++kk)
#pragma unroll
      for (int i = 0; i < 2; ++i)
#pragma unroll
        for (int j = 0; j < 2; ++j)
          acc[2 + i][2 + j] = __builtin_amdgcn_mfma_f32_16x16x32_bf16(
              a[i][kk], b1[j][kk], acc[2 + i][2 + j], 0, 0, 0);
    __builtin_amdgcn_s_setprio(0);
    __builtin_amdgcn_s_barrier();

    // ---- p3 ----
    if (notLast) stageB(0, t0 + 2, 1);
    __builtin_amdgcn_s_setprio(1);
#pragma unroll
    for (int kk = 0; kk < 2; ++kk)
#pragma unroll
      for (int i = 0; i < 2; ++i)
#pragma unroll
        for (int j = 0; j < 2; ++j)
          acc[2 + i][j] = __builtin_amdgcn_mfma_f32_16x16x32_bf16(
              a[i][kk], b0[j][kk], acc[2 + i][j], 0, 0, 0);
    __builtin_amdgcn_s_setprio(0);
    if (notLast) {
      asm volatile("s_waitcnt vmcnt(4)" ::: "memory");
    } else {
      asm volatile("s_waitcnt vmcnt(0)" ::: "memory");
    }
    __builtin_amdgcn_s_barrier();

    // ---- p4 ----
#pragma unroll
    for (int i = 0; i < 2; ++i) {
      a[i][0] = *reinterpret_cast<const bf16x8*>(&A1[aoff + i * 1024 + coff0]);
      a[i][1] = *reinterpret_cast<const bf16x8*>(&A1[aoff + i * 1024 + coff1]);
    }
#pragma unroll
    for (int j = 0; j < 2; ++j) {
      b0[j][0] = *reinterpret_cast<const bf16x8*>(&B1[boff + j * 1024 + coff0]);
      b0[j][1] = *reinterpret_cast<const bf16x8*>(&B1[boff + j * 1024 + coff1]);
    }
    if (notLast) stageA(0, t0 + 2, 0);
    __builtin_amdgcn_s_barrier();
    asm volatile("s_waitcnt lgkmcnt(0)" ::: "memory");
    __builtin_amdgcn_sched_barrier(0);
    __builtin_amdgcn_s_setprio(1);
#pragma unroll
    for (int kk = 0; kk < 2; ++kk)
#pragma unroll
      for (int i = 0; i < 2; ++i)
#pragma unroll
        for (int j = 0; j < 2; ++j)
          acc[i][j] = __builtin_amdgcn_mfma_f32_16x16x32_bf16(
              a[i][kk], b0[j][kk], acc[i][j], 0, 0, 0);
    __builtin_amdgcn_s_setprio(0);
    __builtin_amdgcn_s_barrier();

    // ---- p5 ----
#pragma unroll
    for (int j = 0; j < 2; ++j) {
      b1[j][0] = *reinterpret_cast<const bf16x8*>(&B1[boff + (2 + j) * 1024 + coff0]);
      b1[j][1] = *reinterpret_cast<const bf16x8*>(&B1[boff + (2 + j) * 1024 + coff1]);
    }
    if (notLast) stageA(0, t0 + 2, 1);
    __builtin_amdgcn_s_barrier();
    asm volatile("s_waitcnt lgkmcnt(0)" ::: "memory");
    __builtin_amdgcn_sched_barrier(0);
    __builtin_amdgcn_s_setprio(1);
#pragma unroll
    for (int kk = 0; kk < 2; ++kk)
#pragma unroll
      for (int i = 0; i < 2; ++i)
#pragma unroll
        for (int j = 0; j < 2; ++j)
          acc[i][2 + j] = __builtin_amdgcn_mfma_f32_16x16x32_bf16(
              a[i][kk], b1[j][kk], acc[i][2 + j], 0, 0, 0);
    __builtin_amdgcn_s_setprio(0);
    __builtin_amdgcn_s_barrier();

    // ---- p6 ----
#pragma unroll
    for (int i = 0; i < 2; ++i) {
      a[i][0] = *reinterpret_cast<const bf16x8*>(&A1[aoff + (2 + i) * 1024 + coff0]);
      a[i][1] = *reinterpret_cast<const bf16x8*>(&A1[aoff + (2 + i) * 1024 + coff1]);
    }
    if (notLast) stageB(1, t1 + 2, 0);
    __builtin_amdgcn_s_barrier();
    asm volatile("s_waitcnt lgkmcnt(0)" ::: "memory");
    __builtin_amdgcn_sched_barrier(0);
    __builtin_amdgcn_s_setprio(1);
#pragma unroll
    for (int kk = 0; kk < 2; ++kk)
#pragma unroll
      for (int i = 0; i < 2; ++i)
#pragma unroll
        for (int j = 0; j < 2; ++j)
          acc[2 + i][2 + j] = __builtin_amdgcn_mfma_f32_16x16x32_bf16(
              a[i][kk], b1[j][kk], acc[2 + i][2 + j], 0, 0, 0);
    __builtin_amdgcn_s_setprio(0);
    __builtin_amdgcn_s_barrier();

    // ---- p7 ----
    if (notLast) { stageB(1, t1 + 2, 1); stageA(1, t1 + 2, 0); }
    __builtin_amdgcn_s_setprio(1);
#pragma unroll
    for (int kk = 0; kk < 2; ++kk)
#pragma unroll
      for (int i = 0; i < 2; ++i)
#pragma unroll
        for (int j = 0; j < 2; ++j)
          acc[2 + i][j] = __builtin_amdgcn_mfma_f32_16x16x32_bf16(
              a[i][kk], b0[j][kk], acc[2 + i][j], 0, 0, 0);
    __builtin_amdgcn_s_setprio(0);
    if (notLast) {
      asm volatile("s_waitcnt vmcnt(6)" ::: "memory");
    }
    __builtin_amdgcn_s_barrier();
  }

  int rowB = tm * 128 + wm * 64;
  int colB = tn * 128 + wn * 64;
#pragma unroll
  for (int mi = 0; mi < 4; ++mi)
#pragma unroll
    for (int nj = 0; nj < 4; ++nj) {
      int col = colB + nj * 16 + m16;
      int row0 = rowB + mi * 16 + quad * 4;
#pragma unroll
      for (int t4 = 0; t4 < 4; ++t4)
        C[(size_t)(row0 + t4) * N + col] = acc[mi][nj][t4];
    }
}

// ========= dt_proj single-shot: 128x128 tile, FULL K=128 in one stage ======
// LDS 64 KB (A 32 + B 32) -> 2 blocks/CU. 16 global_load_lds calls, ONE
// vmcnt(0)+barrier (vs 2 full drains in the old BK=64 2-iter version), then
// 64 MFMA (kk-outer, dep distance 16) + bias/softplus epilogue.
// Swizzle: 16B chunk ^ (row&7), both-sides (same algebra as gemm256).
__global__ __launch_bounds__(256, 2) void gemm_dt(
    const unsigned short* __restrict__ A,    // dtin [LL][128]
    const unsigned short* __restrict__ B,    // dtwb [EE][128]
    const float* __restrict__ bias,
    unsigned short* __restrict__ auxB) {     // dtb_buf [LL][EE]
  __shared__ __align__(16) unsigned short As[128 * 128];
  __shared__ __align__(16) unsigned short Bs[128 * 128];

  int bid = blockIdx.x;
  int tnInner = bid & 7;
  int rest = bid >> 3;
  int tm = rest % 16;                 // tilesM = LL/128 = 16
  int tn = (rest / 16) * 8 + tnInner; // tilesN = EE/128 = 32

  int tid = threadIdx.x;
  int lane = tid & 63;
  int wave = tid >> 6;
  int wm = wave & 1, wn = wave >> 1;
  int m16 = lane & 15, quad = lane >> 4;

  const unsigned short* Ab = A + (size_t)tm * 128 * RR;
  const unsigned short* Bb = B + (size_t)tn * 128 * RR;
  int ldsbase = (tid & ~63) * 8;

  // stage full A and B panels: 8 calls each (256 thr x 16B = 16 rows/call)
#pragma unroll
  for (int it = 0; it < 8; ++it) {
    int blk = it * 256 + tid;
    int srow = blk >> 4;               // row 0..127 (16 chunks of 16B per row)
    int gcb = (blk & 15) ^ (srow & 7); // pre-swizzled source chunk
    async_cp16(Ab + (size_t)srow * RR + gcb * 8, &As[it * 2048 + ldsbase]);
  }
#pragma unroll
  for (int it = 0; it < 8; ++it) {
    int blk = it * 256 + tid;
    int srow = blk >> 4;
    int gcb = (blk & 15) ^ (srow & 7);
    async_cp16(Bb + (size_t)srow * RR + gcb * 8, &Bs[it * 2048 + ldsbase]);
  }
  asm volatile("s_waitcnt vmcnt(0)" ::: "memory");
  __builtin_amdgcn_s_barrier();

  f32x4 acc[4][4];
#pragma unroll
  for (int i = 0; i < 4; ++i)
#pragma unroll
    for (int j = 0; j < 4; ++j)
#pragma unroll
      for (int t = 0; t < 4; ++t) acc[i][j][t] = 0.0f;

#pragma unroll
  for (int kk = 0; kk < 4; ++kk) {
    bf16x8 a[4], b[4];
#pragma unroll
    for (int i = 0; i < 4; ++i) {
      int rr = wm * 64 + i * 16 + m16;
      int cb = kk * 4 + quad;
      a[i] = *reinterpret_cast<const bf16x8*>(
          &As[rr * 128 + ((cb ^ (rr & 7)) << 3)]);
    }
#pragma unroll
    for (int j = 0; j < 4; ++j) {
      int rr = wn * 64 + j * 16 + m16;
      int cb = kk * 4 + quad;
      b[j] = *reinterpret_cast<const bf16x8*>(
          &Bs[rr * 128 + ((cb ^ (rr & 7)) << 3)]);
    }
#pragma unroll
    for (int i = 0; i < 4; ++i)
#pragma unroll
      for (int j = 0; j < 4; ++j)
        acc[i][j] =
            __builtin_amdgcn_mfma_f32_16x16x32_bf16(a[i], b[j], acc[i][j], 0, 0, 0);
  }

  int rowB = tm * 128 + wm * 64;
  int colB = tn * 128 + wn * 64;
#pragma unroll
  for (int i = 0; i < 4; ++i)
#pragma unroll
    for (int j = 0; j < 4; ++j) {
      int col = colB + j * 16 + m16;
      float bv = bias[col];
      int row0 = rowB + i * 16 + quad * 4;
#pragma unroll
      for (int t = 0; t < 4; ++t) {
        float x = acc[i][j][t] + bv;
        auxB[(size_t)(row0 + t) * EE + col] = f2bf(softplus_fast(x));
      }
    }
}

// ------------- direct (no-LDS) BT-GEMM for skinny N (x_proj) -------------
__global__ __launch_bounds__(256) void gemm_bt(
    const unsigned short* __restrict__ A,
    const unsigned short* __restrict__ B,
    float* __restrict__ C,
    int M, int N, int K, int tilesN, int splitk) {
  int bid = blockIdx.x;
  int groupSize = 8 * tilesN;
  int g = bid / groupSize, r = bid % groupSize;
  int tm = g * 8 + (r & 7);
  int tn = r >> 3;

  int Kslice = K / splitk;
  int k_begin = blockIdx.y * Kslice;
  int k_end = k_begin + Kslice;

  int tid = threadIdx.x;
  int wave = tid >> 6, lane = tid & 63;
  int wm = wave & 1, wn = wave >> 1;
  int m16 = lane & 15, quad = lane >> 4;
  int rowBase = tm * 64 + wm * 32;
  int colBase = tn * 128 + wn * 64;

  const unsigned short* a0p = A + (size_t)(rowBase + m16) * K + quad * 8;
  const unsigned short* a1p = A + (size_t)(rowBase + 16 + m16) * K + quad * 8;
  const unsigned short* bp[4];
  bool bok[4];
#pragma unroll
  for (int j = 0; j < 4; ++j) {
    int col = colBase + j * 16 + m16;
    bok[j] = (col < N);
    bp[j] = B + (size_t)(bok[j] ? col : 0) * K + quad * 8;
  }

  f32x4 acc[2][4];
#pragma unroll
  for (int i = 0; i < 2; ++i)
#pragma unroll
    for (int j = 0; j < 4; ++j)
#pragma unroll
      for (int t = 0; t < 4; ++t) acc[i][j][t] = 0.0f;

  bf16x8 zero8;
#pragma unroll
  for (int t = 0; t < 8; ++t) zero8[t] = (__bf16)0.0f;

  for (int k = k_begin; k < k_end; k += 32) {
    bf16x8 a0 = *reinterpret_cast<const bf16x8*>(a0p + k);
    bf16x8 a1 = *reinterpret_cast<const bf16x8*>(a1p + k);
    bf16x8 b[4];
#pragma unroll
    for (int j = 0; j < 4; ++j)
      b[j] = bok[j] ? *reinterpret_cast<const bf16x8*>(bp[j] + k) : zero8;
#pragma unroll
    for (int j = 0; j < 4; ++j) {
      acc[0][j] = __builtin_amdgcn_mfma_f32_16x16x32_bf16(a0, b[j], acc[0][j], 0, 0, 0);
      acc[1][j] = __builtin_amdgcn_mfma_f32_16x16x32_bf16(a1, b[j], acc[1][j], 0, 0, 0);
    }
  }

#pragma unroll
  for (int i = 0; i < 2; ++i)
#pragma unroll
    for (int j = 0; j < 4; ++j) {
      int col = colBase + j * 16 + m16;
      if (col >= N) continue;
      int row0 = rowBase + i * 16 + quad * 4;
      if (splitk == 1) {
#pragma unroll
        for (int t = 0; t < 4; ++t)
          C[(size_t)(row0 + t) * N + col] = acc[i][j][t];
      } else {
#pragma unroll
        for (int t = 0; t < 4; ++t)
          atomicAdd(&C[(size_t)(row0 + t) * N + col], acc[i][j][t]);
      }
    }
}

// ------- depthwise causal conv (K=4) + bias + silu, register window -------
__global__ __launch_bounds__(256) void conv_silu_k(
    const float* __restrict__ projh, const float* __restrict__ cw,
    const float* __restrict__ cb, unsigned short* __restrict__ hb) {
  int e = blockIdx.x * 256 + threadIdx.x;
  int l0 = blockIdx.y * 16;
  float w0 = cw[e * 4 + 0], w1 = cw[e * 4 + 1];
  float w2 = cw[e * 4 + 2], w3 = cw[e * 4 + 3];
  float bias = cb[e];
  float xm3 = (l0 >= 3) ? projh[(size_t)(l0 - 3) * EE + e] : 0.0f;
  float xm2 = (l0 >= 2) ? projh[(size_t)(l0 - 2) * EE + e] : 0.0f;
  float xm1 = (l0 >= 1) ? projh[(size_t)(l0 - 1) * EE + e] : 0.0f;
#pragma unroll
  for (int t = 0; t < 16; ++t) {
    int l = l0 + t;
    float x0 = projh[(size_t)l * EE + e];
    float acc = bias + w0 * xm3 + w1 * xm2 + w2 * xm1 + w3 * x0;
    float s = acc / (1.0f + __expf(-acc));
    hb[(size_t)l * EE + e] = f2bf(s);
    xm3 = xm2; xm2 = xm1; xm1 = x0;
  }
}

// ---------------- extract dt rows of ssm -> bf16 [L,128] ----------------
__global__ void dtcast_k(const float* __restrict__ ssm,
                         unsigned short* __restrict__ dtin, int n) {
  int i = blockIdx.x * blockDim.x + threadIdx.x;
  if (i >= n) return;
  int l = i >> 7, r = i & 127;
  dtin[i] = f2bf(ssm[l * 160 + r]);
}

// ================= chunked selective scan (16 states per thread) ===========
__global__ __launch_bounds__(256) void scan_partA(
    const unsigned short* __restrict__ dtb, const unsigned short* __restrict__ hb,
    const float* __restrict__ ssm, const float* __restrict__ A_log,
    float* __restrict__ P, float* __restrict__ S) {
  int e = blockIdx.y * 256 + threadIdx.x;
  int c = blockIdx.x;
  float Aa[16];
#pragma unroll
  for (int q = 0; q < 4; ++q) {
    float4 a = reinterpret_cast<const float4*>(&A_log[(size_t)e * NS])[q];
    Aa[q * 4 + 0] = -__expf(a.x) * 1.44269504f;
    Aa[q * 4 + 1] = -__expf(a.y) * 1.44269504f;
    Aa[q * 4 + 2] = -__expf(a.z) * 1.44269504f;
    Aa[q * 4 + 3] = -__expf(a.w) * 1.44269504f;
  }
  float s[16], p[16];
#pragma unroll
  for (int n = 0; n < 16; ++n) { s[n] = 0.0f; p[n] = 1.0f; }
  int l0 = c * CT;
#pragma unroll 2
  for (int t = 0; t < CT; ++t) {
    int l = l0 + t;
    size_t o = (size_t)l * EE + e;
    float dtv = bf2f(dtb[o]);
    float hv = bf2f(hb[o]);
    float Bv[16];
#pragma unroll
    for (int q = 0; q < 4; ++q)
      *reinterpret_cast<float4*>(&Bv[q * 4]) =
          reinterpret_cast<const float4*>(&ssm[(size_t)l * 160 + 128])[q];
    float z = dtv * hv;
#pragma unroll
    for (int n = 0; n < 16; ++n) {
      float dA = __builtin_amdgcn_exp2f(dtv * Aa[n]);
      s[n] = s[n] * dA + z * Bv[n];
      p[n] *= dA;
    }
  }
  size_t base = ((size_t)c * EE + e) * NS;
#pragma unroll
  for (int q = 0; q < 4; ++q) {
    reinterpret_cast<float4*>(&P[base])[q] = *reinterpret_cast<float4*>(&p[q * 4]);
    reinterpret_cast<float4*>(&S[base])[q] = *reinterpret_cast<float4*>(&s[q * 4]);
  }
}

__global__ __launch_bounds__(256) void scan_chunkB(
    const float* __restrict__ P, float* __restrict__ S) {
  int gidx = blockIdx.x * 256 + threadIdx.x;
  float s = 0.0f;
  float pv = P[gidx], sv = S[gidx];
  for (int c = 0; c < NC; ++c) {
    float pn = 0.0f, sn = 0.0f;
    if (c + 1 < NC) {
      size_t i2 = (size_t)(c + 1) * (EE * NS) + gidx;
      pn = P[i2];
      sn = S[i2];
    }
    float s_next = s * pv + sv;
    S[(size_t)c * (EE * NS) + gidx] = s;
    s = s_next;
    pv = pn; sv = sn;
  }
}

__global__ __launch_bounds__(256) void scan_partC(
    const unsigned short* __restrict__ dtb, const unsigned short* __restrict__ hb,
    const float* __restrict__ ssm, const float* __restrict__ A_log,
    const float* __restrict__ Dp, const unsigned short* __restrict__ sg,
    const float* __restrict__ Sinit, unsigned short* __restrict__ yb) {
  int e = blockIdx.y * 256 + threadIdx.x;
  int c = blockIdx.x;
  float Aa[16];
#pragma unroll
  for (int q = 0; q < 4; ++q) {
    float4 a = reinterpret_cast<const float4*>(&A_log[(size_t)e * NS])[q];
    Aa[q * 4 + 0] = -__expf(a.x) * 1.44269504f;
    Aa[q * 4 + 1] = -__expf(a.y) * 1.44269504f;
    Aa[q * 4 + 2] = -__expf(a.z) * 1.44269504f;
    Aa[q * 4 + 3] = -__expf(a.w) * 1.44269504f;
  }
  float Dv = Dp[e];
  float s[16];
  size_t base = ((size_t)c * EE + e) * NS;
#pragma unroll
  for (int q = 0; q < 4; ++q)
    *reinterpret_cast<float4*>(&s[q * 4]) =
        reinterpret_cast<const float4*>(&Sinit[base])[q];
  int l0 = c * CT;
#pragma unroll 2
  for (int t = 0; t < CT; ++t) {
    int l = l0 + t;
    size_t o = (size_t)l * EE + e;
    float dtv = bf2f(dtb[o]);
    float hv = bf2f(hb[o]);
    float Bv[16], Cv[16];
#pragma unroll
    for (int q = 0; q < 4; ++q) {
      *reinterpret_cast<float4*>(&Bv[q * 4]) =
          reinterpret_cast<const float4*>(&ssm[(size_t)l * 160 + 128])[q];
      *reinterpret_cast<float4*>(&Cv[q * 4]) =
          reinterpret_cast<const float4*>(&ssm[(size_t)l * 160 + 144])[q];
    }
    float z = dtv * hv;
    float y = 0.0f;
#pragma unroll
    for (int n = 0; n < 16; ++n) {
      float dA = __builtin_amdgcn_exp2f(dtv * Aa[n]);
      s[n] = s[n] * dA + z * Bv[n];
      y += s[n] * Cv[n];
    }
    float gv = bf2f(sg[o]);  // pre-activated silu(gate)
    float yv = (y + hv * Dv) * gv;
    yb[o] = f2bf(yv);
  }
}

extern "C" void kernel_launch(void* const* d_in, const int* in_sizes, int n_in,
                              void* d_out, int out_size, void* d_ws, size_t ws_size,
                              hipStream_t stream) {
  const float* hs   = (const float*)d_in[0];
  const float* w1   = (const float*)d_in[1];
  const float* cw   = (const float*)d_in[2];
  const float* cb   = (const float*)d_in[3];
  const float* xw   = (const float*)d_in[4];
  const float* dtw  = (const float*)d_in[5];
  const float* dtb  = (const float*)d_in[6];
  const float* Alog = (const float*)d_in[7];
  const float* Dp   = (const float*)d_in[8];
  const float* ow   = (const float*)d_in[9];
  float* out = (float*)d_out;

  char* ws = (char*)d_ws;
  size_t off = 0;
  auto alloc = [&](size_t b) {
    char* p = ws + off;
    off += (b + 255) & ~(size_t)255;
    return p;
  };
  float* projh = (float*)alloc((size_t)LL * EE * 4);                 // 33.5 MB
  unsigned short* sg  = (unsigned short*)alloc((size_t)LL * EE * 2); // 16.8 MB
  unsigned short* hb  = (unsigned short*)alloc((size_t)LL * EE * 2); // 16.8 MB
  unsigned short* dtb_buf = (unsigned short*)alloc((size_t)LL * EE * 2); // 16.8 MB
  unsigned short* w1b = (unsigned short*)alloc((size_t)2 * EE * HH * 2); // 33.5 MB
  unsigned short* hsb = (unsigned short*)alloc((size_t)LL * HH * 2);
  unsigned short* yb  = (unsigned short*)alloc((size_t)LL * EE * 2);
  unsigned short* owb = (unsigned short*)alloc((size_t)HH * EE * 2);
  unsigned short* xwb = (unsigned short*)alloc((size_t)160 * EE * 2);
  float* ssm = (float*)alloc((size_t)LL * 160 * 4);
  unsigned short* dtin = (unsigned short*)alloc((size_t)LL * RR * 2);
  unsigned short* dtwb = (unsigned short*)alloc((size_t)EE * RR * 2);
  float* Pbuf = (float*)alloc((size_t)NC * EE * NS * 4);             // 16.8 MB
  float* Sbuf = (float*)alloc((size_t)NC * EE * NS * 4);             // 16.8 MB

  // 0) fused prep: 5 input casts + ssm zero in ONE launch
  prep_k<<<P_C5 / 256, 256, 0, stream>>>(hs, hsb, w1, w1b, xw, xwb, dtw, dtwb,
                                         ow, owb, ssm);

  // 1) proj = hs @ in_proj_w^T [2048, 8192]; 256^2 8-phase counted-vmcnt.
  //    epilogue: h -> projh f32, gate -> silu -> sg bf16   (~76us measured)
  {
    int tilesM = LL / 256;          // 8
    int tilesN = (2 * EE) / 256;    // 32  -> 256 blocks, 1/CU
    gemm256<2><<<dim3(tilesM * tilesN, 1), 512, 0, stream>>>(
        hsb, w1b, nullptr, LL, 2 * EE, HH, tilesM, 1, projh, sg);
  }
  // 2) causal depthwise conv + silu -> h (bf16)
  conv_silu_k<<<dim3(EE / 256, LL / 16), 256, 0, stream>>>(projh, cw, cb, hb);
  // 3) ssm = h @ x_proj_w^T [2048, 160] k=4096, split-K=8 (skinny N; atomics
  //    into small L2-resident target — R5-proven)
  {
    int tilesN = (160 + 127) / 128, tilesM = LL / 64;
    gemm_bt<<<dim3(tilesM * tilesN, 8), 256, 0, stream>>>(
        hb, xwb, ssm, LL, 160, EE, tilesN, 8);
  }
  // 4) dt input slice -> bf16
  dtcast_k<<<(LL * RR + 255) / 256, 256, 0, stream>>>(ssm, dtin, LL * RR);
  // 5) dt = softplus(dtin @ dt_proj_w^T + dtb) -> bf16  [2048,4096] k=128.
  //    Single-shot LDS kernel: one vmcnt(0)+barrier instead of two drains.
  gemm_dt<<<16 * 32, 256, 0, stream>>>(dtin, dtwb, dtb, dtb_buf);
  // 6) chunked selective scan + gating -> y (bf16)
  scan_partA<<<dim3(NC, EE / 256), 256, 0, stream>>>(dtb_buf, hb, ssm, Alog,
                                                     Pbuf, Sbuf);
  scan_chunkB<<<EE * NS / 256, 256, 0, stream>>>(Pbuf, Sbuf);
  scan_partC<<<dim3(NC, EE / 256), 256, 0, stream>>>(dtb_buf, hb, ssm, Alog, Dp,
                                                     sg, Sbuf, yb);
  // 7) out = y @ out_proj_w^T [2048, 2048] k=4096; 128^2 8-phase, no split-K,
  //    direct stores (no atomics, no pre-zero)
  {
    int tilesM = LL / 128, tilesN = HH / 128;  // 16 x 16 = 256
    gemm128p<<<dim3(tilesM * tilesN, 1), 256, 0, stream>>>(
        yb, owb, out, LL, HH, EE, tilesM);
  }
}

// Round 9
// 394.308 us; speedup vs baseline: 1.0326x; 1.0036x over previous
//
#include <hip/hip_runtime.h>

#define LL 2048
#define HH 2048
#define EE 4096
#define NS 16
#define RR 128
#define CT 32            // chunk timesteps
#define NC (LL / CT)     // 64 chunks
#define BM 128
#define BN 128
#define BK 64

typedef __bf16 bf16x8 __attribute__((ext_vector_type(8)));
typedef float f32x4 __attribute__((ext_vector_type(4)));

__device__ __forceinline__ unsigned short f2bf(float f) {
  union { float f; unsigned int u; } v; v.f = f;
  unsigned int r = v.u + 0x7fffu + ((v.u >> 16) & 1u);
  return (unsigned short)(r >> 16);
}

__device__ __forceinline__ float bf2f(unsigned short u) {
  union { unsigned int i; float f; } v;
  v.i = ((unsigned int)u) << 16;
  return v.f;
}

// softplus via native transcendentals only (NO libm log1pf — non-inline ocml
// call forces VGPR save/restore in high-pressure epilogues)
__device__ __forceinline__ float softplus_fast(float x) {
  if (x > 20.0f) return x;
  float e = __builtin_amdgcn_exp2f(1.44269504f * x);
  return 0.69314718f * __builtin_amdgcn_logf(1.0f + e);
}

__device__ __forceinline__ void async_cp16(const unsigned short* g,
                                           unsigned short* l) {
  __builtin_amdgcn_global_load_lds(
      (const __attribute__((address_space(1))) unsigned int*)g,
      (__attribute__((address_space(3))) unsigned int*)l, 16, 0, 0);
}

// ============ fused prep: 5 bf16 casts + 1 zero fill, ONE launch ==========
#define P_C0 (LL * HH / 4)               // hs -> hsb
#define P_C1 (P_C0 + 2 * EE * HH / 4)    // w1 -> w1b
#define P_C2 (P_C1 + 160 * EE / 4)       // xw -> xwb
#define P_C3 (P_C2 + EE * RR / 4)        // dtw -> dtwb
#define P_C4 (P_C3 + HH * EE / 4)        // ow -> owb
#define P_C5 (P_C4 + LL * 160 / 4)       // zero ssm

__global__ __launch_bounds__(256) void prep_k(
    const float* __restrict__ hs, unsigned short* __restrict__ hsb,
    const float* __restrict__ w1, unsigned short* __restrict__ w1b,
    const float* __restrict__ xw, unsigned short* __restrict__ xwb,
    const float* __restrict__ dtw, unsigned short* __restrict__ dtwb,
    const float* __restrict__ ow, unsigned short* __restrict__ owb,
    float* __restrict__ ssm) {
  int i = blockIdx.x * 256 + threadIdx.x;
  const float* src;
  unsigned short* dst;
  int k;
  if (i < P_C0)      { src = hs;  dst = hsb;  k = i; }
  else if (i < P_C1) { src = w1;  dst = w1b;  k = i - P_C0; }
  else if (i < P_C2) { src = xw;  dst = xwb;  k = i - P_C1; }
  else if (i < P_C3) { src = dtw; dst = dtwb; k = i - P_C2; }
  else if (i < P_C4) { src = ow;  dst = owb;  k = i - P_C3; }
  else {
    float4 z; z.x = z.y = z.z = z.w = 0.0f;
    reinterpret_cast<float4*>(ssm)[i - P_C4] = z;
    return;
  }
  float4 v = reinterpret_cast<const float4*>(src)[k];
  ushort4 o;
  o.x = f2bf(v.x); o.y = f2bf(v.y); o.z = f2bf(v.z); o.w = f2bf(v.w);
  reinterpret_cast<ushort4*>(dst)[k] = o;
}

// ======== 256x256 8-phase BT-GEMM, kk-SPLIT phases (R8 rebalance) ==========
// 512 threads = 8 waves (2Mx4N), per-wave 128x64. BK=64, dbuf LDS 128 KiB.
// Phases split by K-half (kk), not C-column-half: every phase = 16 MFMA into
// 16 DISTINCT accs (dep distance 16) with balanced ds_reads 8/8/4/4:
//  p0: aL kk0(4)+b kk0(4); stage A(t1)h0+h1;  MFMA acc[0..3][*] (kk0)
//  p1: aL kk1(4)+b kk1(4);                    MFMA acc[0..3][*] (kk1)
//  p2: a-hi kk0(4);        stage B(t0+2)h0;   MFMA acc[4..7][*] x b-kk0
//  p3: a-hi kk1(4);        stage B(t0+2)h1;   MFMA acc[4..7][*] x b-kk1; vmcnt(4)
//  p4-p7 mirror on buf1; stages A(t0+2)h0/h1, B(t1+2)h0/h1; p7 vmcnt(4)
// vmcnt(4) ledger: 12 outstanding -> completes oldest 8 = exactly the next
// tile's A+B halves. Stage-target deadness verified per-phase (each region's
// last reader is >=1 barrier before the stage issue). Swizzle: 16B chunk ^
// (row&7), both-sides. SQ_LDS_BANK_CONFLICT=0 measured.
// NOTE: atomic split-K epilogue measured ~95us (cross-XCD RMW) — never use.
// EPI: 2 = in_proj (cols<EE -> f32 auxF; cols>=EE -> silu bf16 auxB)
template <int EPI>
__global__ __launch_bounds__(512, 2) void gemm256(
    const unsigned short* __restrict__ A,
    const unsigned short* __restrict__ B,
    float* __restrict__ C,
    int M, int N, int K, int tilesM, int splitk,
    float* __restrict__ auxF, unsigned short* __restrict__ auxB) {
  __shared__ __align__(16) unsigned short As[2][16384];
  __shared__ __align__(16) unsigned short Bs[2][16384];

  int bid = blockIdx.x;
  int tnInner = bid & 7;             // XCD-locality
  int rest = bid >> 3;
  int tm = rest % tilesM;
  int tn = (rest / tilesM) * 8 + tnInner;

  int Kslice = K / splitk;
  int k_begin = blockIdx.y * Kslice;
  int NT = Kslice / 64;              // even, >= 2

  int tid = threadIdx.x;
  int lane = tid & 63;
  int wave = tid >> 6;               // 0..7
  int wm = wave >> 2;                // 0..1
  int wn = wave & 3;                 // 0..3
  int m16 = lane & 15, quad = lane >> 4;

  const unsigned short* Ab = A + (size_t)tm * 256 * K;
  const unsigned short* Bb = B + (size_t)tn * 256 * K;

  int rowS = tid >> 3;
  int gcbS = (tid & 7) ^ (rowS & 7);
  int ldsWB = (tid & ~63) * 8;

  int sw = m16 & 7;
  int coff0 = (quad ^ sw) << 3;
  int coff1 = ((4 + quad) ^ sw) << 3;
  int aoff = (wm * 128 + m16) * 64;
  int boff = (wn * 64 + m16) * 64;

  f32x4 acc[8][4];
#pragma unroll
  for (int i = 0; i < 8; ++i)
#pragma unroll
    for (int j = 0; j < 4; ++j)
#pragma unroll
      for (int t = 0; t < 4; ++t) acc[i][j][t] = 0.0f;

  auto stageA = [&](int bufb, int t, int h) {
    int kt = k_begin + t * 64;
    unsigned short* dst = &As[bufb][0];
#pragma unroll
    for (int c = 2 * h; c < 2 * h + 2; ++c)
      async_cp16(Ab + (size_t)(c * 64 + rowS) * K + kt + gcbS * 8,
                 dst + c * 4096 + ldsWB);
  };
  auto stageB = [&](int bufb, int t, int h) {
    int kt = k_begin + t * 64;
    unsigned short* dst = &Bs[bufb][0];
#pragma unroll
    for (int c = 2 * h; c < 2 * h + 2; ++c)
      async_cp16(Bb + (size_t)(c * 64 + rowS) * K + kt + gcbS * 8,
                 dst + c * 4096 + ldsWB);
  };

  // prologue: tile0 full (8) + B(1) h0,h1 (4); vmcnt(4) -> tile0 landed,
  // B(1) 4 in flight (matches steady-state p7-exit)
  stageA(0, 0, 0); stageA(0, 0, 1);
  stageB(0, 0, 0); stageB(0, 0, 1);
  stageB(1, 1, 0); stageB(1, 1, 1);
  asm volatile("s_waitcnt vmcnt(4)" ::: "memory");
  __builtin_amdgcn_s_barrier();

  bf16x8 aL[4], b0[4], b1[4];

  for (int t0 = 0; t0 < NT; t0 += 2) {
    int t1 = t0 + 1;
    bool notLast = (t0 + 2 < NT);
    unsigned short* A0 = &As[0][0];
    unsigned short* B0 = &Bs[0][0];
    unsigned short* A1 = &As[1][0];
    unsigned short* B1 = &Bs[1][0];

    // ---- p0: a-lo kk0 + b kk0; stage A(t1) h0+h1; MFMA rows 0-3 ----
#pragma unroll
    for (int i = 0; i < 4; ++i)
      aL[i] = *reinterpret_cast<const bf16x8*>(&A0[aoff + i * 1024 + coff0]);
#pragma unroll
    for (int j = 0; j < 4; ++j)
      b0[j] = *reinterpret_cast<const bf16x8*>(&B0[boff + j * 1024 + coff0]);
    stageA(1, t1, 0); stageA(1, t1, 1);
    __builtin_amdgcn_s_barrier();
    asm volatile("s_waitcnt lgkmcnt(0)" ::: "memory");
    __builtin_amdgcn_sched_barrier(0);
    __builtin_amdgcn_s_setprio(1);
#pragma unroll
    for (int i = 0; i < 4; ++i)
#pragma unroll
      for (int j = 0; j < 4; ++j)
        acc[i][j] = __builtin_amdgcn_mfma_f32_16x16x32_bf16(
            aL[i], b0[j], acc[i][j], 0, 0, 0);
    __builtin_amdgcn_s_setprio(0);
    __builtin_amdgcn_s_barrier();

    // ---- p1: a-lo kk1 + b kk1; MFMA rows 0-3 ----
#pragma unroll
    for (int i = 0; i < 4; ++i)
      aL[i] = *reinterpret_cast<const bf16x8*>(&A0[aoff + i * 1024 + coff1]);
#pragma unroll
    for (int j = 0; j < 4; ++j)
      b1[j] = *reinterpret_cast<const bf16x8*>(&B0[boff + j * 1024 + coff1]);
    __builtin_amdgcn_s_barrier();
    asm volatile("s_waitcnt lgkmcnt(0)" ::: "memory");
    __builtin_amdgcn_sched_barrier(0);
    __builtin_amdgcn_s_setprio(1);
#pragma unroll
    for (int i = 0; i < 4; ++i)
#pragma unroll
      for (int j = 0; j < 4; ++j)
        acc[i][j] = __builtin_amdgcn_mfma_f32_16x16x32_bf16(
            aL[i], b1[j], acc[i][j], 0, 0, 0);
    __builtin_amdgcn_s_setprio(0);
    __builtin_amdgcn_s_barrier();

    // ---- p2: a-hi kk0 (reuse b0); stage B(t0+2)h0; MFMA rows 4-7 ----
#pragma unroll
    for (int i = 0; i < 4; ++i)
      aL[i] = *reinterpret_cast<const bf16x8*>(&A0[aoff + (4 + i) * 1024 + coff0]);
    if (notLast) stageB(0, t0 + 2, 0);
    __builtin_amdgcn_s_barrier();
    asm volatile("s_waitcnt lgkmcnt(0)" ::: "memory");
    __builtin_amdgcn_sched_barrier(0);
    __builtin_amdgcn_s_setprio(1);
#pragma unroll
    for (int i = 0; i < 4; ++i)
#pragma unroll
      for (int j = 0; j < 4; ++j)
        acc[4 + i][j] = __builtin_amdgcn_mfma_f32_16x16x32_bf16(
            aL[i], b0[j], acc[4 + i][j], 0, 0, 0);
    __builtin_amdgcn_s_setprio(0);
    __builtin_amdgcn_s_barrier();

    // ---- p3: a-hi kk1 (reuse b1); stage B(t0+2)h1; MFMA rows 4-7; vmcnt ----
#pragma unroll
    for (int i = 0; i < 4; ++i)
      aL[i] = *reinterpret_cast<const bf16x8*>(&A0[aoff + (4 + i) * 1024 + coff1]);
    if (notLast) stageB(0, t0 + 2, 1);
    __builtin_amdgcn_s_barrier();
    asm volatile("s_waitcnt lgkmcnt(0)" ::: "memory");
    __builtin_amdgcn_sched_barrier(0);
    __builtin_amdgcn_s_setprio(1);
#pragma unroll
    for (int i = 0; i < 4; ++i)
#pragma unroll
      for (int j = 0; j < 4; ++j)
        acc[4 + i][j] = __builtin_amdgcn_mfma_f32_16x16x32_bf16(
            aL[i], b1[j], acc[4 + i][j], 0, 0, 0);
    __builtin_amdgcn_s_setprio(0);
    if (notLast) {
      asm volatile("s_waitcnt vmcnt(4)" ::: "memory");  // A(t1)+B(t1) landed
    } else {
      asm volatile("s_waitcnt vmcnt(0)" ::: "memory");
    }
    __builtin_amdgcn_s_barrier();

    // ---- p4: a-lo kk0 + b kk0 (buf1); stage A(t0+2)h0; MFMA rows 0-3 ----
#pragma unroll
    for (int i = 0; i < 4; ++i)
      aL[i] = *reinterpret_cast<const bf16x8*>(&A1[aoff + i * 1024 + coff0]);
#pragma unroll
    for (int j = 0; j < 4; ++j)
      b0[j] = *reinterpret_cast<const bf16x8*>(&B1[boff + j * 1024 + coff0]);
    if (notLast) stageA(0, t0 + 2, 0);
    __builtin_amdgcn_s_barrier();
    asm volatile("s_waitcnt lgkmcnt(0)" ::: "memory");
    __builtin_amdgcn_sched_barrier(0);
    __builtin_amdgcn_s_setprio(1);
#pragma unroll
    for (int i = 0; i < 4; ++i)
#pragma unroll
      for (int j = 0; j < 4; ++j)
        acc[i][j] = __builtin_amdgcn_mfma_f32_16x16x32_bf16(
            aL[i], b0[j], acc[i][j], 0, 0, 0);
    __builtin_amdgcn_s_setprio(0);
    __builtin_amdgcn_s_barrier();

    // ---- p5: a-lo kk1 + b kk1; stage A(t0+2)h1; MFMA rows 0-3 ----
#pragma unroll
    for (int i = 0; i < 4; ++i)
      aL[i] = *reinterpret_cast<const bf16x8*>(&A1[aoff + i * 1024 + coff1]);
#pragma unroll
    for (int j = 0; j < 4; ++j)
      b1[j] = *reinterpret_cast<const bf16x8*>(&B1[boff + j * 1024 + coff1]);
    if (notLast) stageA(0, t0 + 2, 1);
    __builtin_amdgcn_s_barrier();
    asm volatile("s_waitcnt lgkmcnt(0)" ::: "memory");
    __builtin_amdgcn_sched_barrier(0);
    __builtin_amdgcn_s_setprio(1);
#pragma unroll
    for (int i = 0; i < 4; ++i)
#pragma unroll
      for (int j = 0; j < 4; ++j)
        acc[i][j] = __builtin_amdgcn_mfma_f32_16x16x32_bf16(
            aL[i], b1[j], acc[i][j], 0, 0, 0);
    __builtin_amdgcn_s_setprio(0);
    __builtin_amdgcn_s_barrier();

    // ---- p6: a-hi kk0 (reuse b0); stage B(t1+2)h0; MFMA rows 4-7 ----
#pragma unroll
    for (int i = 0; i < 4; ++i)
      aL[i] = *reinterpret_cast<const bf16x8*>(&A1[aoff + (4 + i) * 1024 + coff0]);
    if (notLast) stageB(1, t1 + 2, 0);
    __builtin_amdgcn_s_barrier();
    asm volatile("s_waitcnt lgkmcnt(0)" ::: "memory");
    __builtin_amdgcn_sched_barrier(0);
    __builtin_amdgcn_s_setprio(1);
#pragma unroll
    for (int i = 0; i < 4; ++i)
#pragma unroll
      for (int j = 0; j < 4; ++j)
        acc[4 + i][j] = __builtin_amdgcn_mfma_f32_16x16x32_bf16(
            aL[i], b0[j], acc[4 + i][j], 0, 0, 0);
    __builtin_amdgcn_s_setprio(0);
    __builtin_amdgcn_s_barrier();

    // ---- p7: a-hi kk1 (reuse b1); stage B(t1+2)h1; MFMA rows 4-7; vmcnt ----
#pragma unroll
    for (int i = 0; i < 4; ++i)
      aL[i] = *reinterpret_cast<const bf16x8*>(&A1[aoff + (4 + i) * 1024 + coff1]);
    if (notLast) stageB(1, t1 + 2, 1);
    __builtin_amdgcn_s_barrier();
    asm volatile("s_waitcnt lgkmcnt(0)" ::: "memory");
    __builtin_amdgcn_sched_barrier(0);
    __builtin_amdgcn_s_setprio(1);
#pragma unroll
    for (int i = 0; i < 4; ++i)
#pragma unroll
      for (int j = 0; j < 4; ++j)
        acc[4 + i][j] = __builtin_amdgcn_mfma_f32_16x16x32_bf16(
            aL[i], b1[j], acc[4 + i][j], 0, 0, 0);
    __builtin_amdgcn_s_setprio(0);
    if (notLast) {
      asm volatile("s_waitcnt vmcnt(4)" ::: "memory");  // A+B(t0+2) landed
    }
    __builtin_amdgcn_s_barrier();
  }

  // ---------------- epilogue ----------------
  int rowB = tm * 256 + wm * 128;
  int colB = tn * 256 + wn * 64;
  if constexpr (EPI == 2) {
    if (colB < EE) {
#pragma unroll
      for (int mi = 0; mi < 8; ++mi)
#pragma unroll
        for (int nj = 0; nj < 4; ++nj) {
          int col = colB + nj * 16 + m16;
          int row0 = rowB + mi * 16 + quad * 4;
#pragma unroll
          for (int t4 = 0; t4 < 4; ++t4)
            auxF[(size_t)(row0 + t4) * EE + col] = acc[mi][nj][t4];
        }
    } else {
#pragma unroll
      for (int mi = 0; mi < 8; ++mi)
#pragma unroll
        for (int nj = 0; nj < 4; ++nj) {
          int cg = colB + nj * 16 + m16 - EE;
          int row0 = rowB + mi * 16 + quad * 4;
#pragma unroll
          for (int t4 = 0; t4 < 4; ++t4) {
            float v = acc[mi][nj][t4];
            float s = v / (1.0f + __expf(-v));
            auxB[(size_t)(row0 + t4) * EE + cg] = f2bf(s);
          }
        }
    }
  }
}

// ====== 128x128 8-phase BT-GEMM, NO split-K, direct store (out_proj) =======
// R5-proven ~30us. Unchanged this round.
__global__ __launch_bounds__(256, 2) void gemm128p(
    const unsigned short* __restrict__ A,
    const unsigned short* __restrict__ B,
    float* __restrict__ C,
    int M, int N, int K, int tilesM) {
  __shared__ __align__(16) unsigned short As[2][8192];
  __shared__ __align__(16) unsigned short Bs[2][8192];

  int bid = blockIdx.x;
  int tnInner = bid & 7;
  int rest = bid >> 3;
  int tm = rest % tilesM;
  int tn = (rest / tilesM) * 8 + tnInner;

  int NT = K / 64;

  int tid = threadIdx.x;
  int lane = tid & 63;
  int wave = tid >> 6;
  int wm = wave >> 1;
  int wn = wave & 1;
  int m16 = lane & 15, quad = lane >> 4;

  const unsigned short* Ab = A + (size_t)tm * 128 * K;
  const unsigned short* Bb = B + (size_t)tn * 128 * K;

  int rowS = tid >> 3;
  int gcbS = (tid & 7) ^ (rowS & 7);
  int ldsWB = (tid & ~63) * 8;

  int sw = m16 & 7;
  int coff0 = (quad ^ sw) << 3;
  int coff1 = ((4 + quad) ^ sw) << 3;
  int aoff = (wm * 64 + m16) * 64;
  int boff = (wn * 64 + m16) * 64;

  f32x4 acc[4][4];
#pragma unroll
  for (int i = 0; i < 4; ++i)
#pragma unroll
    for (int j = 0; j < 4; ++j)
#pragma unroll
      for (int t = 0; t < 4; ++t) acc[i][j][t] = 0.0f;

  auto stageA = [&](int bufb, int t, int h) {
    int kt = t * 64;
    unsigned short* dst = &As[bufb][0];
#pragma unroll
    for (int c = 2 * h; c < 2 * h + 2; ++c)
      async_cp16(Ab + (size_t)(c * 32 + rowS) * K + kt + gcbS * 8,
                 dst + c * 2048 + ldsWB);
  };
  auto stageB = [&](int bufb, int t, int h) {
    int kt = t * 64;
    unsigned short* dst = &Bs[bufb][0];
#pragma unroll
    for (int c = 2 * h; c < 2 * h + 2; ++c)
      async_cp16(Bb + (size_t)(c * 32 + rowS) * K + kt + gcbS * 8,
                 dst + c * 2048 + ldsWB);
  };

  stageA(0, 0, 0); stageA(0, 0, 1);
  stageB(0, 0, 0); stageB(0, 0, 1);
  stageB(1, 1, 0); stageB(1, 1, 1);
  stageA(1, 1, 0);
  asm volatile("s_waitcnt vmcnt(6)" ::: "memory");
  __builtin_amdgcn_s_barrier();

  bf16x8 a[2][2], b0[2][2], b1[2][2];

  for (int t0 = 0; t0 < NT; t0 += 2) {
    int t1 = t0 + 1;
    bool notLast = (t0 + 2 < NT);
    unsigned short* A0 = &As[0][0];
    unsigned short* B0 = &Bs[0][0];
    unsigned short* A1 = &As[1][0];
    unsigned short* B1 = &Bs[1][0];

    // ---- p0 ----
#pragma unroll
    for (int i = 0; i < 2; ++i) {
      a[i][0] = *reinterpret_cast<const bf16x8*>(&A0[aoff + i * 1024 + coff0]);
      a[i][1] = *reinterpret_cast<const bf16x8*>(&A0[aoff + i * 1024 + coff1]);
    }
#pragma unroll
    for (int j = 0; j < 2; ++j) {
      b0[j][0] = *reinterpret_cast<const bf16x8*>(&B0[boff + j * 1024 + coff0]);
      b0[j][1] = *reinterpret_cast<const bf16x8*>(&B0[boff + j * 1024 + coff1]);
    }
    stageA(1, t1, 1);
    __builtin_amdgcn_s_barrier();
    asm volatile("s_waitcnt lgkmcnt(0)" ::: "memory");
    __builtin_amdgcn_sched_barrier(0);
    __builtin_amdgcn_s_setprio(1);
#pragma unroll
    for (int kk = 0; kk < 2; ++kk)
#pragma unroll
      for (int i = 0; i < 2; ++i)
#pragma unroll
        for (int j = 0; j < 2; ++j)
          acc[i][j] = __builtin_amdgcn_mfma_f32_16x16x32_bf16(
              a[i][kk], b0[j][kk], acc[i][j], 0, 0, 0);
    __builtin_amdgcn_s_setprio(0);
    __builtin_amdgcn_s_barrier();

    // ---- p1 ----
#pragma unroll
    for (int j = 0; j < 2; ++j) {
      b1[j][0] = *reinterpret_cast<const bf16x8*>(&B0[boff + (2 + j) * 1024 + coff0]);
      b1[j][1] = *reinterpret_cast<const bf16x8*>(&B0[boff + (2 + j) * 1024 + coff1]);
    }
    __builtin_amdgcn_s_barrier();
    asm volatile("s_waitcnt lgkmcnt(0)" ::: "memory");
    __builtin_amdgcn_sched_barrier(0);
    __builtin_amdgcn_s_setprio(1);
#pragma unroll
    for (int kk = 0; kk < 2; ++kk)
#pragma unroll
      for (int i = 0; i < 2; ++i)
#pragma unroll
        for (int j = 0; j < 2; ++j)
          acc[i][2 + j] = __builtin_amdgcn_mfma_f32_16x16x32_bf16(
              a[i][kk], b1[j][kk], acc[i][2 + j], 0, 0, 0);
    __builtin_amdgcn_s_setprio(0);
    __builtin_amdgcn_s_barrier();

    // ---- p2 ----
#pragma unroll
    for (int i = 0; i < 2; ++i) {
      a[i][0] = *reinterpret_cast<const bf16x8*>(&A0[aoff + (2 + i) * 1024 + coff0]);
      a[i][1] = *reinterpret_cast<const bf16x8*>(&A0[aoff + (2 + i) * 1024 + coff1]);
    }
    if (notLast) stageB(0, t0 + 2, 0);
    __builtin_amdgcn_s_barrier();
    asm volatile("s_waitcnt lgkmcnt(0)" ::: "memory");
    __builtin_amdgcn_sched_barrier(0);
    __builtin_amdgcn_s_setprio(1);
#pragma unroll
    for (int kk = 0; kk < 2; ++kk)
#pragma unroll
      for (int i = 0; i < 2; ++i)
#pragma unroll
        for (int j = 0; j < 2; ++j)
          acc[2 + i][2 + j] = __builtin_amdgcn_mfma_f32_16x16x32_bf16(
              a[i][kk], b1[j][kk], acc[2 + i][2 + j], 0, 0, 0);
    __builtin_amdgcn_s_setprio(0);
    __builtin_amdgcn_s_barrier();

    // ---- p3 ----
    if (notLast) stageB(0, t0 + 2, 1);
    __builtin_amdgcn_s_setprio(1);
#pragma unroll
    for (int kk = 0; kk < 2; ++kk)
#pragma unroll
      for (int i = 0; i < 2; ++i)
#pragma unroll
        for (int j = 0; j < 2; ++j)
          acc[2 + i][j] = __builtin_amdgcn_mfma_f32_16x16x32_bf16(
              a[i][kk], b0[j][kk], acc[2 + i][j], 0, 0, 0);
    __builtin_amdgcn_s_setprio(0);
    if (notLast) {
      asm volatile("s_waitcnt vmcnt(4)" ::: "memory");
    } else {
      asm volatile("s_waitcnt vmcnt(0)" ::: "memory");
    }
    __builtin_amdgcn_s_barrier();

    // ---- p4 ----
#pragma unroll
    for (int i = 0; i < 2; ++i) {
      a[i][0] = *reinterpret_cast<const bf16x8*>(&A1[aoff + i * 1024 + coff0]);
      a[i][1] = *reinterpret_cast<const bf16x8*>(&A1[aoff + i * 1024 + coff1]);
    }
#pragma unroll
    for (int j = 0; j < 2; ++j) {
      b0[j][0] = *reinterpret_cast<const bf16x8*>(&B1[boff + j * 1024 + coff0]);
      b0[j][1] = *reinterpret_cast<const bf16x8*>(&B1[boff + j * 1024 + coff1]);
    }
    if (notLast) stageA(0, t0 + 2, 0);
    __builtin_amdgcn_s_barrier();
    asm volatile("s_waitcnt lgkmcnt(0)" ::: "memory");
    __builtin_amdgcn_sched_barrier(0);
    __builtin_amdgcn_s_setprio(1);
#pragma unroll
    for (int kk = 0; kk < 2; ++kk)
#pragma unroll
      for (int i = 0; i < 2; ++i)
#pragma unroll
        for (int j = 0; j < 2; ++j)
          acc[i][j] = __builtin_amdgcn_mfma_f32_16x16x32_bf16(
              a[i][kk], b0[j][kk], acc[i][j], 0, 0, 0);
    __builtin_amdgcn_s_setprio(0);
    __builtin_amdgcn_s_barrier();

    // ---- p5 ----
#pragma unroll
    for (int j = 0; j < 2; ++j) {
      b1[j][0] = *reinterpret_cast<const bf16x8*>(&B1[boff + (2 + j) * 1024 + coff0]);
      b1[j][1] = *reinterpret_cast<const bf16x8*>(&B1[boff + (2 + j) * 1024 + coff1]);
    }
    if (notLast) stageA(0, t0 + 2, 1);
    __builtin_amdgcn_s_barrier();
    asm volatile("s_waitcnt lgkmcnt(0)" ::: "memory");
    __builtin_amdgcn_sched_barrier(0);
    __builtin_amdgcn_s_setprio(1);
#pragma unroll
    for (int kk = 0; kk < 2; ++kk)
#pragma unroll
      for (int i = 0; i < 2; ++i)
#pragma unroll
        for (int j = 0; j < 2; ++j)
          acc[i][2 + j] = __builtin_amdgcn_mfma_f32_16x16x32_bf16(
              a[i][kk], b1[j][kk], acc[i][2 + j], 0, 0, 0);
    __builtin_amdgcn_s_setprio(0);
    __builtin_amdgcn_s_barrier();

    // ---- p6 ----
#pragma unroll
    for (int i = 0; i < 2; ++i) {
      a[i][0] = *reinterpret_cast<const bf16x8*>(&A1[aoff + (2 + i) * 1024 + coff0]);
      a[i][1] = *reinterpret_cast<const bf16x8*>(&A1[aoff + (2 + i) * 1024 + coff1]);
    }
    if (notLast) stageB(1, t1 + 2, 0);
    __builtin_amdgcn_s_barrier();
    asm volatile("s_waitcnt lgkmcnt(0)" ::: "memory");
    __builtin_amdgcn_sched_barrier(0);
    __builtin_amdgcn_s_setprio(1);
#pragma unroll
    for (int kk = 0; kk < 2; ++kk)
#pragma unroll
      for (int i = 0; i < 2; ++i)
#pragma unroll
        for (int j = 0; j < 2; ++j)
          acc[2 + i][2 + j] = __builtin_amdgcn_mfma_f32_16x16x32_bf16(
              a[i][kk], b1[j][kk], acc[2 + i][2 + j], 0, 0, 0);
    __builtin_amdgcn_s_setprio(0);
    __builtin_amdgcn_s_barrier();

    // ---- p7 ----
    if (notLast) { stageB(1, t1 + 2, 1); stageA(1, t1 + 2, 0); }
    __builtin_amdgcn_s_setprio(1);
#pragma unroll
    for (int kk = 0; kk < 2; ++kk)
#pragma unroll
      for (int i = 0; i < 2; ++i)
#pragma unroll
        for (int j = 0; j < 2; ++j)
          acc[2 + i][j] = __builtin_amdgcn_mfma_f32_16x16x32_bf16(
              a[i][kk], b0[j][kk], acc[2 + i][j], 0, 0, 0);
    __builtin_amdgcn_s_setprio(0);
    if (notLast) {
      asm volatile("s_waitcnt vmcnt(6)" ::: "memory");
    }
    __builtin_amdgcn_s_barrier();
  }

  int rowB = tm * 128 + wm * 64;
  int colB = tn * 128 + wn * 64;
#pragma unroll
  for (int mi = 0; mi < 4; ++mi)
#pragma unroll
    for (int nj = 0; nj < 4; ++nj) {
      int col = colB + nj * 16 + m16;
      int row0 = rowB + mi * 16 + quad * 4;
#pragma unroll
      for (int t4 = 0; t4 < 4; ++t4)
        C[(size_t)(row0 + t4) * N + col] = acc[mi][nj][t4];
    }
}

// ============ LDS-staged bf16 BT-GEMM (128x128) — dt_proj (393-anchor) =====
// EPI 4 = +bias[col], softplus, bf16 store to auxB
template <int EPI>
__global__ __launch_bounds__(256) void gemm_lds_t(
    const unsigned short* __restrict__ A,
    const unsigned short* __restrict__ B,
    float* __restrict__ C,
    int M, int N, int K, int tilesM, int splitk,
    const float* __restrict__ bias, float* __restrict__ auxF,
    unsigned short* __restrict__ auxB) {
  __shared__ __align__(16) unsigned short As[BM * BK];
  __shared__ __align__(16) unsigned short Bs[BN * BK];

  int bid = blockIdx.x;
  int tnInner = bid & 7;
  int rest = bid >> 3;
  int tm = rest % tilesM;
  int tnOuter = rest / tilesM;
  int tn = tnOuter * 8 + tnInner;

  int Kslice = K / splitk;
  int k_begin = blockIdx.y * Kslice;
  int k_end = k_begin + Kslice;

  int tid = threadIdx.x;
  int lane = tid & 63;
  int wave = tid >> 6;
  int wm = wave & 1, wn = wave >> 1;
  int m16 = lane & 15, quad = lane >> 4;

  const unsigned short* Ab = A + (size_t)tm * BM * K;
  const unsigned short* Bb = B + (size_t)tn * BN * K;

  int srow[4], sgcb[4];
#pragma unroll
  for (int it = 0; it < 4; ++it) {
    int blk = it * 256 + tid;
    srow[it] = blk >> 3;
    sgcb[it] = (blk & 7) ^ (srow[it] & 7);
  }
  int ldsbase = (tid & ~63) * 8;

  f32x4 acc[4][4];
#pragma unroll
  for (int i = 0; i < 4; ++i)
#pragma unroll
    for (int j = 0; j < 4; ++j)
#pragma unroll
      for (int t = 0; t < 4; ++t) acc[i][j][t] = 0.0f;

  for (int k0 = k_begin; k0 < k_end; k0 += BK) {
    __syncthreads();
#pragma unroll
    for (int it = 0; it < 4; ++it)
      async_cp16(Ab + (size_t)srow[it] * K + k0 + sgcb[it] * 8,
                 &As[it * 2048 + ldsbase]);
#pragma unroll
    for (int it = 0; it < 4; ++it)
      async_cp16(Bb + (size_t)srow[it] * K + k0 + sgcb[it] * 8,
                 &Bs[it * 2048 + ldsbase]);
    __syncthreads();
#pragma unroll
    for (int kk = 0; kk < 2; ++kk) {
      bf16x8 a[4], b[4];
#pragma unroll
      for (int i = 0; i < 4; ++i) {
        int rr = wm * 64 + i * 16 + m16;
        int cb = (kk << 2) + quad;
        a[i] = *reinterpret_cast<const bf16x8*>(
            &As[rr * BK + ((cb ^ (rr & 7)) << 3)]);
      }
#pragma unroll
      for (int j = 0; j < 4; ++j) {
        int rr = wn * 64 + j * 16 + m16;
        int cb = (kk << 2) + quad;
        b[j] = *reinterpret_cast<const bf16x8*>(
            &Bs[rr * BK + ((cb ^ (rr & 7)) << 3)]);
      }
#pragma unroll
      for (int i = 0; i < 4; ++i)
#pragma unroll
        for (int j = 0; j < 4; ++j)
          acc[i][j] =
              __builtin_amdgcn_mfma_f32_16x16x32_bf16(a[i], b[j], acc[i][j], 0, 0, 0);
    }
  }

  int rowB = tm * BM + wm * 64;
  int colB = tn * BN + wn * 64;
#pragma unroll
  for (int i = 0; i < 4; ++i)
#pragma unroll
    for (int j = 0; j < 4; ++j) {
      int col = colB + j * 16 + m16;
      float bv = bias[col];
      int row0 = rowB + i * 16 + quad * 4;
#pragma unroll
      for (int t = 0; t < 4; ++t) {
        float x = acc[i][j][t] + bv;
        auxB[(size_t)(row0 + t) * EE + col] = f2bf(softplus_fast(x));
      }
    }
}

// ------------- direct (no-LDS) BT-GEMM for skinny N (x_proj) -------------
__global__ __launch_bounds__(256) void gemm_bt(
    const unsigned short* __restrict__ A,
    const unsigned short* __restrict__ B,
    float* __restrict__ C,
    int M, int N, int K, int tilesN, int splitk) {
  int bid = blockIdx.x;
  int groupSize = 8 * tilesN;
  int g = bid / groupSize, r = bid % groupSize;
  int tm = g * 8 + (r & 7);
  int tn = r >> 3;

  int Kslice = K / splitk;
  int k_begin = blockIdx.y * Kslice;
  int k_end = k_begin + Kslice;

  int tid = threadIdx.x;
  int wave = tid >> 6, lane = tid & 63;
  int wm = wave & 1, wn = wave >> 1;
  int m16 = lane & 15, quad = lane >> 4;
  int rowBase = tm * 64 + wm * 32;
  int colBase = tn * 128 + wn * 64;

  const unsigned short* a0p = A + (size_t)(rowBase + m16) * K + quad * 8;
  const unsigned short* a1p = A + (size_t)(rowBase + 16 + m16) * K + quad * 8;
  const unsigned short* bp[4];
  bool bok[4];
#pragma unroll
  for (int j = 0; j < 4; ++j) {
    int col = colBase + j * 16 + m16;
    bok[j] = (col < N);
    bp[j] = B + (size_t)(bok[j] ? col : 0) * K + quad * 8;
  }

  f32x4 acc[2][4];
#pragma unroll
  for (int i = 0; i < 2; ++i)
#pragma unroll
    for (int j = 0; j < 4; ++j)
#pragma unroll
      for (int t = 0; t < 4; ++t) acc[i][j][t] = 0.0f;

  bf16x8 zero8;
#pragma unroll
  for (int t = 0; t < 8; ++t) zero8[t] = (__bf16)0.0f;

  for (int k = k_begin; k < k_end; k += 32) {
    bf16x8 a0 = *reinterpret_cast<const bf16x8*>(a0p + k);
    bf16x8 a1 = *reinterpret_cast<const bf16x8*>(a1p + k);
    bf16x8 b[4];
#pragma unroll
    for (int j = 0; j < 4; ++j)
      b[j] = bok[j] ? *reinterpret_cast<const bf16x8*>(bp[j] + k) : zero8;
#pragma unroll
    for (int j = 0; j < 4; ++j) {
      acc[0][j] = __builtin_amdgcn_mfma_f32_16x16x32_bf16(a0, b[j], acc[0][j], 0, 0, 0);
      acc[1][j] = __builtin_amdgcn_mfma_f32_16x16x32_bf16(a1, b[j], acc[1][j], 0, 0, 0);
    }
  }

#pragma unroll
  for (int i = 0; i < 2; ++i)
#pragma unroll
    for (int j = 0; j < 4; ++j) {
      int col = colBase + j * 16 + m16;
      if (col >= N) continue;
      int row0 = rowBase + i * 16 + quad * 4;
      if (splitk == 1) {
#pragma unroll
        for (int t = 0; t < 4; ++t)
          C[(size_t)(row0 + t) * N + col] = acc[i][j][t];
      } else {
#pragma unroll
        for (int t = 0; t < 4; ++t)
          atomicAdd(&C[(size_t)(row0 + t) * N + col], acc[i][j][t]);
      }
    }
}

// ------- depthwise causal conv (K=4) + bias + silu, register window -------
__global__ __launch_bounds__(256) void conv_silu_k(
    const float* __restrict__ projh, const float* __restrict__ cw,
    const float* __restrict__ cb, unsigned short* __restrict__ hb) {
  int e = blockIdx.x * 256 + threadIdx.x;
  int l0 = blockIdx.y * 16;
  float w0 = cw[e * 4 + 0], w1 = cw[e * 4 + 1];
  float w2 = cw[e * 4 + 2], w3 = cw[e * 4 + 3];
  float bias = cb[e];
  float xm3 = (l0 >= 3) ? projh[(size_t)(l0 - 3) * EE + e] : 0.0f;
  float xm2 = (l0 >= 2) ? projh[(size_t)(l0 - 2) * EE + e] : 0.0f;
  float xm1 = (l0 >= 1) ? projh[(size_t)(l0 - 1) * EE + e] : 0.0f;
#pragma unroll
  for (int t = 0; t < 16; ++t) {
    int l = l0 + t;
    float x0 = projh[(size_t)l * EE + e];
    float acc = bias + w0 * xm3 + w1 * xm2 + w2 * xm1 + w3 * x0;
    float s = acc / (1.0f + __expf(-acc));
    hb[(size_t)l * EE + e] = f2bf(s);
    xm3 = xm2; xm2 = xm1; xm1 = x0;
  }
}

// ---------------- extract dt rows of ssm -> bf16 [L,128] ----------------
__global__ void dtcast_k(const float* __restrict__ ssm,
                         unsigned short* __restrict__ dtin, int n) {
  int i = blockIdx.x * blockDim.x + threadIdx.x;
  if (i >= n) return;
  int l = i >> 7, r = i & 127;
  dtin[i] = f2bf(ssm[l * 160 + r]);
}

// ================= chunked selective scan (16 states per thread) ===========
__global__ __launch_bounds__(256) void scan_partA(
    const unsigned short* __restrict__ dtb, const unsigned short* __restrict__ hb,
    const float* __restrict__ ssm, const float* __restrict__ A_log,
    float* __restrict__ P, float* __restrict__ S) {
  int e = blockIdx.y * 256 + threadIdx.x;
  int c = blockIdx.x;
  float Aa[16];
#pragma unroll
  for (int q = 0; q < 4; ++q) {
    float4 a = reinterpret_cast<const float4*>(&A_log[(size_t)e * NS])[q];
    Aa[q * 4 + 0] = -__expf(a.x) * 1.44269504f;
    Aa[q * 4 + 1] = -__expf(a.y) * 1.44269504f;
    Aa[q * 4 + 2] = -__expf(a.z) * 1.44269504f;
    Aa[q * 4 + 3] = -__expf(a.w) * 1.44269504f;
  }
  float s[16], p[16];
#pragma unroll
  for (int n = 0; n < 16; ++n) { s[n] = 0.0f; p[n] = 1.0f; }
  int l0 = c * CT;
#pragma unroll 2
  for (int t = 0; t < CT; ++t) {
    int l = l0 + t;
    size_t o = (size_t)l * EE + e;
    float dtv = bf2f(dtb[o]);
    float hv = bf2f(hb[o]);
    float Bv[16];
#pragma unroll
    for (int q = 0; q < 4; ++q)
      *reinterpret_cast<float4*>(&Bv[q * 4]) =
          reinterpret_cast<const float4*>(&ssm[(size_t)l * 160 + 128])[q];
    float z = dtv * hv;
#pragma unroll
    for (int n = 0; n < 16; ++n) {
      float dA = __builtin_amdgcn_exp2f(dtv * Aa[n]);
      s[n] = s[n] * dA + z * Bv[n];
      p[n] *= dA;
    }
  }
  size_t base = ((size_t)c * EE + e) * NS;
#pragma unroll
  for (int q = 0; q < 4; ++q) {
    reinterpret_cast<float4*>(&P[base])[q] = *reinterpret_cast<float4*>(&p[q * 4]);
    reinterpret_cast<float4*>(&S[base])[q] = *reinterpret_cast<float4*>(&s[q * 4]);
  }
}

__global__ __launch_bounds__(256) void scan_chunkB(
    const float* __restrict__ P, float* __restrict__ S) {
  int gidx = blockIdx.x * 256 + threadIdx.x;
  float s = 0.0f;
  float pv = P[gidx], sv = S[gidx];
  for (int c = 0; c < NC; ++c) {
    float pn = 0.0f, sn = 0.0f;
    if (c + 1 < NC) {
      size_t i2 = (size_t)(c + 1) * (EE * NS) + gidx;
      pn = P[i2];
      sn = S[i2];
    }
    float s_next = s * pv + sv;
    S[(size_t)c * (EE * NS) + gidx] = s;
    s = s_next;
    pv = pn; sv = sn;
  }
}

__global__ __launch_bounds__(256) void scan_partC(
    const unsigned short* __restrict__ dtb, const unsigned short* __restrict__ hb,
    const float* __restrict__ ssm, const float* __restrict__ A_log,
    const float* __restrict__ Dp, const unsigned short* __restrict__ sg,
    const float* __restrict__ Sinit, unsigned short* __restrict__ yb) {
  int e = blockIdx.y * 256 + threadIdx.x;
  int c = blockIdx.x;
  float Aa[16];
#pragma unroll
  for (int q = 0; q < 4; ++q) {
    float4 a = reinterpret_cast<const float4*>(&A_log[(size_t)e * NS])[q];
    Aa[q * 4 + 0] = -__expf(a.x) * 1.44269504f;
    Aa[q * 4 + 1] = -__expf(a.y) * 1.44269504f;
    Aa[q * 4 + 2] = -__expf(a.z) * 1.44269504f;
    Aa[q * 4 + 3] = -__expf(a.w) * 1.44269504f;
  }
  float Dv = Dp[e];
  float s[16];
  size_t base = ((size_t)c * EE + e) * NS;
#pragma unroll
  for (int q = 0; q < 4; ++q)
    *reinterpret_cast<float4*>(&s[q * 4]) =
        reinterpret_cast<const float4*>(&Sinit[base])[q];
  int l0 = c * CT;
#pragma unroll 2
  for (int t = 0; t < CT; ++t) {
    int l = l0 + t;
    size_t o = (size_t)l * EE + e;
    float dtv = bf2f(dtb[o]);
    float hv = bf2f(hb[o]);
    float Bv[16], Cv[16];
#pragma unroll
    for (int q = 0; q < 4; ++q) {
      *reinterpret_cast<float4*>(&Bv[q * 4]) =
          reinterpret_cast<const float4*>(&ssm[(size_t)l * 160 + 128])[q];
      *reinterpret_cast<float4*>(&Cv[q * 4]) =
          reinterpret_cast<const float4*>(&ssm[(size_t)l * 160 + 144])[q];
    }
    float z = dtv * hv;
    float y = 0.0f;
#pragma unroll
    for (int n = 0; n < 16; ++n) {
      float dA = __builtin_amdgcn_exp2f(dtv * Aa[n]);
      s[n] = s[n] * dA + z * Bv[n];
      y += s[n] * Cv[n];
    }
    float gv = bf2f(sg[o]);  // pre-activated silu(gate)
    float yv = (y + hv * Dv) * gv;
    yb[o] = f2bf(yv);
  }
}

extern "C" void kernel_launch(void* const* d_in, const int* in_sizes, int n_in,
                              void* d_out, int out_size, void* d_ws, size_t ws_size,
                              hipStream_t stream) {
  const float* hs   = (const float*)d_in[0];
  const float* w1   = (const float*)d_in[1];
  const float* cw   = (const float*)d_in[2];
  const float* cb   = (const float*)d_in[3];
  const float* xw   = (const float*)d_in[4];
  const float* dtw  = (const float*)d_in[5];
  const float* dtb  = (const float*)d_in[6];
  const float* Alog = (const float*)d_in[7];
  const float* Dp   = (const float*)d_in[8];
  const float* ow   = (const float*)d_in[9];
  float* out = (float*)d_out;

  char* ws = (char*)d_ws;
  size_t off = 0;
  auto alloc = [&](size_t b) {
    char* p = ws + off;
    off += (b + 255) & ~(size_t)255;
    return p;
  };
  float* projh = (float*)alloc((size_t)LL * EE * 4);                 // 33.5 MB
  unsigned short* sg  = (unsigned short*)alloc((size_t)LL * EE * 2); // 16.8 MB
  unsigned short* hb  = (unsigned short*)alloc((size_t)LL * EE * 2); // 16.8 MB
  unsigned short* dtb_buf = (unsigned short*)alloc((size_t)LL * EE * 2); // 16.8 MB
  unsigned short* w1b = (unsigned short*)alloc((size_t)2 * EE * HH * 2); // 33.5 MB
  unsigned short* hsb = (unsigned short*)alloc((size_t)LL * HH * 2);
  unsigned short* yb  = (unsigned short*)alloc((size_t)LL * EE * 2);
  unsigned short* owb = (unsigned short*)alloc((size_t)HH * EE * 2);
  unsigned short* xwb = (unsigned short*)alloc((size_t)160 * EE * 2);
  float* ssm = (float*)alloc((size_t)LL * 160 * 4);
  unsigned short* dtin = (unsigned short*)alloc((size_t)LL * RR * 2);
  unsigned short* dtwb = (unsigned short*)alloc((size_t)EE * RR * 2);
  float* Pbuf = (float*)alloc((size_t)NC * EE * NS * 4);             // 16.8 MB
  float* Sbuf = (float*)alloc((size_t)NC * EE * NS * 4);             // 16.8 MB

  // 0) fused prep: 5 input casts + ssm zero in ONE launch
  prep_k<<<P_C5 / 256, 256, 0, stream>>>(hs, hsb, w1, w1b, xw, xwb, dtw, dtwb,
                                         ow, owb, ssm);

  // 1) proj = hs @ in_proj_w^T [2048, 8192]; kk-split 8-phase counted-vmcnt.
  //    epilogue: h -> projh f32, gate -> silu -> sg bf16
  {
    int tilesM = LL / 256;          // 8
    int tilesN = (2 * EE) / 256;    // 32  -> 256 blocks, 1/CU
    gemm256<2><<<dim3(tilesM * tilesN, 1), 512, 0, stream>>>(
        hsb, w1b, nullptr, LL, 2 * EE, HH, tilesM, 1, projh, sg);
  }
  // 2) causal depthwise conv + silu -> h (bf16)
  conv_silu_k<<<dim3(EE / 256, LL / 16), 256, 0, stream>>>(projh, cw, cb, hb);
  // 3) ssm = h @ x_proj_w^T [2048, 160] k=4096, split-K=8 (skinny N; atomics
  //    into small L2-resident target — R5-proven)
  {
    int tilesN = (160 + 127) / 128, tilesM = LL / 64;
    gemm_bt<<<dim3(tilesM * tilesN, 8), 256, 0, stream>>>(
        hb, xwb, ssm, LL, 160, EE, tilesN, 8);
  }
  // 4) dt input slice -> bf16
  dtcast_k<<<(LL * RR + 255) / 256, 256, 0, stream>>>(ssm, dtin, LL * RR);
  // 5) dt = softplus(dtin @ dt_proj_w^T + dtb) -> bf16 [2048,4096] k=128 —
  //    393-anchor config (gemm_dt single-shot measured == this, R8)
  {
    int tilesN = EE / BN, tilesM = LL / BM;
    gemm_lds_t<4><<<dim3(tilesM * tilesN, 1), 256, 0, stream>>>(
        dtin, dtwb, nullptr, LL, EE, RR, tilesM, 1, dtb, nullptr, dtb_buf);
  }
  // 6) chunked selective scan + gating -> y (bf16)
  scan_partA<<<dim3(NC, EE / 256), 256, 0, stream>>>(dtb_buf, hb, ssm, Alog,
                                                     Pbuf, Sbuf);
  scan_chunkB<<<EE * NS / 256, 256, 0, stream>>>(Pbuf, Sbuf);
  scan_partC<<<dim3(NC, EE / 256), 256, 0, stream>>>(dtb_buf, hb, ssm, Alog, Dp,
                                                     sg, Sbuf, yb);
  // 7) out = y @ out_proj_w^T [2048, 2048] k=4096; 128^2 8-phase, no split-K,
  //    direct stores (no atomics, no pre-zero)
  {
    int tilesM = LL / 128, tilesN = HH / 128;  // 16 x 16 = 256
    gemm128p<<<dim3(tilesM * tilesN, 1), 256, 0, stream>>>(
        yb, owb, out, LL, HH, EE, tilesM);
  }
}